// Round 1
// baseline (270.716 us; speedup 1.0000x reference)
//
#include <hip/hip_runtime.h>
#include <hip/hip_bf16.h>

// GraphSAGE 3-layer: 40 -> 64 -> 128 -> 3, mean aggregation over fixed edges.
// R14: traffic + dispatch cuts on the R13 structure:
//  - pairs packed into one int (s:17b | dloc:11b): halves bucket stores.
//  - Acat eliminated: k_gemm reads mean (NN x 64, zero-padded) + root direct
//    from xb/h1 with guarded zero chunks (K=128 unchanged).
//  - k_cvt fused into k_bucket's dispatch (independent blocks).

static constexpr int NN = 100000;
static constexpr int EE = 1600000;
static constexpr int NB = (NN + 255) / 256;   // 391 scan blocks
static constexpr int NRANGE = 64;
static constexpr int RSIZE = (NN + NRANGE - 1) / NRANGE;   // 1563 (< 2^11)
static constexpr int NBUCKET = 8 * NRANGE;                 // 512
static constexpr int CAP = 4096;     // per-bucket capacity (mean ~3130, ~17 sigma)
static constexpr int BCHUNK = 2048;  // edges per block (8 per thread)
static constexpr int BUCKET_BLOCKS = (EE + BCHUNK - 1) / BCHUNK;  // 782
static constexpr int CVT_BLOCKS = (NN * 40 / 8 + 255) / 256;      // 1954

typedef __attribute__((ext_vector_type(8))) short short8;
typedef __attribute__((ext_vector_type(4))) float f32x4;

__device__ __forceinline__ float bf2f(unsigned short u) {
    union { unsigned int i; float f; } c; c.i = ((unsigned int)u) << 16; return c.f;
}
__device__ __forceinline__ unsigned short f2bf(float f) {
    union { float f; unsigned int i; } c; c.f = f;
    unsigned int x = c.i;
    return (unsigned short)((x + 0x7fffu + ((x >> 16) & 1u)) >> 16);   // RNE
}

// ---------------- phase 1 (fused): bucket edges (packed) + x->bf16 convert ----------------
__global__ __launch_bounds__(256) void k_bucket_cvt(const int* __restrict__ src, const int* __restrict__ dst,
                                                    int* __restrict__ pcur, unsigned int* __restrict__ pairs,
                                                    const float* __restrict__ x, unsigned short* __restrict__ xb) {
    __shared__ int cnt[NRANGE];
    __shared__ int base[NRANGE];
    const int tid = threadIdx.x;
    if (blockIdx.x >= BUCKET_BLOCKS) {
        // ---- convert branch: fp32 -> bf16 rows of x ----
        int i = (blockIdx.x - BUCKET_BLOCKS) * 256 + tid;
        if (i < NN * 40 / 8) {
            const float4* p = (const float4*)(x + (size_t)i * 8);
            float4 a = p[0], b = p[1];
            short8 v;
            v[0] = (short)f2bf(a.x); v[1] = (short)f2bf(a.y); v[2] = (short)f2bf(a.z); v[3] = (short)f2bf(a.w);
            v[4] = (short)f2bf(b.x); v[5] = (short)f2bf(b.y); v[6] = (short)f2bf(b.z); v[7] = (short)f2bf(b.w);
            *(short8*)(xb + (size_t)i * 8) = v;
        }
        return;
    }
    // ---- bucket branch: block-local reservation, packed (s | dloc<<17) ----
    const int part = blockIdx.x & 7;            // this block's XCD tag (round-robin)
    const int e0 = blockIdx.x * BCHUNK;
    if (tid < NRANGE) cnt[tid] = 0;
    __syncthreads();
    int r_[8], lp_[8];
    unsigned int p_[8];
#pragma unroll
    for (int j = 0; j < 8; ++j) {
        int e = e0 + j * 256 + tid;
        r_[j] = -1;
        if (e < EE) {
            int d = dst[e];
            int s = src[e];
            int r = d / RSIZE;                  // const-divide -> magic mul
            r_[j] = r;
            p_[j] = (unsigned int)s | ((unsigned int)(d - r * RSIZE) << 17);
            lp_[j] = atomicAdd(&cnt[r], 1);     // fast LDS atomic
        }
    }
    __syncthreads();
    if (tid < NRANGE) {
        int c = cnt[tid];
        base[tid] = (c > 0) ? atomicAdd(&pcur[(part << 6) | tid], c) : 0;  // 1 global RMW / bucket / block
    }
    __syncthreads();
#pragma unroll
    for (int j = 0; j < 8; ++j) {
        if (r_[j] >= 0) {
            int pos = base[r_[j]] + lp_[j];
            if (pos < CAP) pairs[(size_t)((part << 6) | r_[j]) * CAP + pos] = p_[j];
        }
    }
}

// ---------------- phase 1.5: per-range degree count in LDS (no global atomics) ----------------
__global__ __launch_bounds__(1024) void k_degr(const unsigned int* __restrict__ pairs, const int* __restrict__ pcur,
                                               int* __restrict__ deg) {
    __shared__ int ldeg[RSIZE];
    const int r = blockIdx.x;                   // 0..63; XCD = r%8
    const int lo = r * RSIZE;
    const int hi = (lo + RSIZE < NN) ? lo + RSIZE : NN;
    for (int t = threadIdx.x; t < RSIZE; t += 1024) ldeg[t] = 0;
    __syncthreads();
    for (int p = 0; p < 8; ++p) {
        int b = (p << 6) | r;
        int len = pcur[b];
        if (len > CAP) len = CAP;
        const unsigned int* base = pairs + (size_t)b * CAP;
        for (int i = threadIdx.x; i < len; i += 1024)
            atomicAdd(&ldeg[base[i] >> 17], 1);
    }
    __syncthreads();
    for (int t = threadIdx.x; t < hi - lo; t += 1024)
        deg[lo + t] = ldeg[t];                  // coalesced full-line write, once
}

// ---------------- phase 2: scatter into CSR with per-range LDS cursors ----------------
__global__ __launch_bounds__(1024) void k_scatter2(const unsigned int* __restrict__ pairs,
                                                   const int* __restrict__ pcur,
                                                   const int* __restrict__ row_start,
                                                   int* __restrict__ csr_src) {
    __shared__ int lcur[RSIZE];
    const int r = blockIdx.x;                   // 0..63; XCD = r%8
    const int lo = r * RSIZE;
    for (int t = threadIdx.x; t < RSIZE; t += 1024) lcur[t] = 0;
    __syncthreads();
    for (int p = 0; p < 8; ++p) {
        int b = (p << 6) | r;
        int len = pcur[b];
        if (len > CAP) len = CAP;
        const unsigned int* base = pairs + (size_t)b * CAP;
        for (int i = threadIdx.x; i < len; i += 1024) {
            unsigned int pk = base[i];
            int dloc = pk >> 17;
            int lp = atomicAdd(&lcur[dloc], 1);             // LDS atomic
            csr_src[row_start[lo + dloc] + lp] = (int)(pk & 0x1FFFFu);
        }
    }
}

// ---------------- hierarchical scan: block sums ----------------
__global__ __launch_bounds__(256) void k_bsum(const int* __restrict__ deg, int* __restrict__ bsum) {
    int i = blockIdx.x * 256 + threadIdx.x;
    int v = (i < NN) ? deg[i] : 0;
    int lane = threadIdx.x & 63, wid = threadIdx.x >> 6;
#pragma unroll
    for (int d = 32; d; d >>= 1) v += __shfl_down(v, d, 64);
    __shared__ int wsum[4];
    if (lane == 0) wsum[wid] = v;
    __syncthreads();
    if (threadIdx.x == 0) bsum[blockIdx.x] = wsum[0] + wsum[1] + wsum[2] + wsum[3];
}

// ---------------- scan of 391 block sums (one block) ----------------
__global__ __launch_bounds__(512) void k_bscan(const int* __restrict__ bsum, int* __restrict__ boff,
                                               int* __restrict__ row_start) {
    __shared__ int s[512];
    int tid = threadIdx.x;
    int v = (tid < NB) ? bsum[tid] : 0;
    s[tid] = v;
    __syncthreads();
    for (int d = 1; d < 512; d <<= 1) {
        int t = (tid >= d) ? s[tid - d] : 0;
        __syncthreads();
        s[tid] += t;
        __syncthreads();
    }
    if (tid < NB) boff[tid] = s[tid] - v;   // exclusive
    if (tid == 0) row_start[NN] = EE;
}

// ---------------- final scan: row_start + deg_inv ----------------
__global__ __launch_bounds__(256) void k_scan2(const int* __restrict__ deg, const int* __restrict__ boff,
                                               int* __restrict__ row_start, float* __restrict__ deg_inv) {
    int tid = threadIdx.x, lane = tid & 63, wid = tid >> 6;
    int i = blockIdx.x * 256 + tid;
    int v = (i < NN) ? deg[i] : 0;
    int inc = v;
#pragma unroll
    for (int d = 1; d < 64; d <<= 1) {
        int t = __shfl_up(inc, d, 64);
        if (lane >= d) inc += t;
    }
    __shared__ int wsum[4];
    if (lane == 63) wsum[wid] = inc;
    __syncthreads();
    if (tid == 0) {
        int s = 0;
#pragma unroll
        for (int j = 0; j < 4; ++j) { int t = wsum[j]; wsum[j] = s; s += t; }
    }
    __syncthreads();
    if (i < NN) {
        row_start[i] = boff[blockIdx.x] + wsum[wid] + (inc - v);
        deg_inv[i] = (v > 0) ? 1.0f / (float)v : 0.0f;
    }
}

// ---------------- bf16 mean-aggregate into mean buffer (NN x 64, zero-padded) ----------------
template<int Fin>
__global__ __launch_bounds__(256) void k_meanb(const unsigned short* __restrict__ xin,
                                               const int* __restrict__ row_start,
                                               const int* __restrict__ csr_src,
                                               const float* __restrict__ deg_inv,
                                               unsigned short* __restrict__ meanb) {
    constexpr int CH = Fin / 8;     // data chunks (5 or 8)
    int gid = blockIdx.x * 256 + threadIdx.x;
    int node = gid >> 3;
    int c = gid & 7;
    if (node >= NN) return;
    float acc[8] = {0, 0, 0, 0, 0, 0, 0, 0};
    if (c < CH) {
        const unsigned short* xq = xin + c * 8;
        int rs = row_start[node], re = row_start[node + 1];
        int k = rs;
        for (; k + 4 <= re; k += 4) {
            int s0 = csr_src[k], s1 = csr_src[k + 1], s2 = csr_src[k + 2], s3 = csr_src[k + 3];
            short8 v0 = *(const short8*)(xq + (size_t)s0 * Fin);
            short8 v1 = *(const short8*)(xq + (size_t)s1 * Fin);
            short8 v2 = *(const short8*)(xq + (size_t)s2 * Fin);
            short8 v3 = *(const short8*)(xq + (size_t)s3 * Fin);
#pragma unroll
            for (int j = 0; j < 8; ++j)
                acc[j] += (bf2f((unsigned short)v0[j]) + bf2f((unsigned short)v1[j]))
                        + (bf2f((unsigned short)v2[j]) + bf2f((unsigned short)v3[j]));
        }
        for (; k < re; ++k) {
            short8 v0 = *(const short8*)(xq + (size_t)csr_src[k] * Fin);
#pragma unroll
            for (int j = 0; j < 8; ++j) acc[j] += bf2f((unsigned short)v0[j]);
        }
        float di = deg_inv[node];
#pragma unroll
        for (int j = 0; j < 8; ++j) acc[j] *= di;
    }
    short8 m;
#pragma unroll
    for (int j = 0; j < 8; ++j) m[j] = (c < CH) ? (short)f2bf(acc[j]) : (short)0;
    *(short8*)(meanb + (size_t)node * 64 + c * 8) = m;
}

// ---------------- MFMA GEMM: out = relu?(mean@Wl^T + root@Wr^T + b) ----------------
// K = 128 (mean 64-padded | root 64-padded); root read DIRECTLY from xb/h1
// (stride Fin), zero chunks where k >= Fin. B frags: k<64 -> Wl, else Wr.
template<int Fin, int Fout, bool RELU>
__global__ __launch_bounds__(256) void k_gemm(const unsigned short* __restrict__ meanb,
                                              const unsigned short* __restrict__ root,
                                              const float* __restrict__ Wl,
                                              const float* __restrict__ bias,
                                              const float* __restrict__ Wr,
                                              unsigned short* __restrict__ out) {
    constexpr int KS = 4;                       // 2 mean + 2 root
    constexpr int TILES = Fout / 16;
    __shared__ short sB[TILES * KS * 64 * 8];
    const int lane = threadIdx.x & 63;
    for (int idx = threadIdx.x; idx < TILES * KS * 64; idx += 256) {
        int l = idx & 63;
        int ks = (idx >> 6) % KS;
        int t = idx / (64 * KS);
        int o = t * 16 + (l & 15);
        int kbase = ks * 32 + (l >> 4) * 8;
        short8 v;
#pragma unroll
        for (int j = 0; j < 8; ++j) {
            int k = kbase + j;
            float w;
            if (k < 64) w = (k < Fin) ? Wl[(size_t)o * Fin + k] : 0.f;
            else { int k2 = k - 64; w = (k2 < Fin) ? Wr[(size_t)o * Fin + k2] : 0.f; }
            v[j] = (short)f2bf(w);
        }
        *(short8*)&sB[idx * 8] = v;
    }
    __syncthreads();
    float bias_t[TILES];
#pragma unroll
    for (int t = 0; t < TILES; ++t) bias_t[t] = bias[t * 16 + (lane & 15)];

    const int kchunk = (lane >> 4) * 8;         // 0,8,16,24 within a 32-wide ks step
    const int wave = blockIdx.x * 4 + (threadIdx.x >> 6);
    const int nchunks = NN / 32;                // 3125
    for (int ci = wave; ci < nchunks; ci += gridDim.x * 4) {
        int nbase = ci * 32;
        int row0 = nbase + (lane & 15);
        const unsigned short* m0 = meanb + (size_t)row0 * 64 + kchunk;
        const unsigned short* r0 = root + (size_t)row0 * Fin + kchunk;
        short8 af[2][KS];
#pragma unroll
        for (int ks = 0; ks < 2; ++ks) {        // mean halves (always valid: 64-padded)
            af[0][ks] = *(const short8*)(m0 + ks * 32);
            af[1][ks] = *(const short8*)(m0 + 16 * 64 + ks * 32);
        }
#pragma unroll
        for (int ks = 0; ks < 2; ++ks) {        // root halves (guard k >= Fin chunks)
            int k2 = ks * 32 + kchunk;
            if (k2 + 8 <= Fin) {
                af[0][2 + ks] = *(const short8*)(r0 + ks * 32);
                af[1][2 + ks] = *(const short8*)(r0 + (size_t)16 * Fin + ks * 32);
            } else {
                short8 zz = {0, 0, 0, 0, 0, 0, 0, 0};
                af[0][2 + ks] = zz;
                af[1][2 + ks] = zz;
            }
        }
        f32x4 acc[2][TILES];
#pragma unroll
        for (int m = 0; m < 2; ++m)
#pragma unroll
            for (int t = 0; t < TILES; ++t) acc[m][t] = (f32x4){0.f, 0.f, 0.f, 0.f};
#pragma unroll
        for (int t = 0; t < TILES; ++t)
#pragma unroll
            for (int ks = 0; ks < KS; ++ks) {
                short8 bf = *(const short8*)&sB[((t * KS + ks) * 64 + lane) * 8];
                acc[0][t] = __builtin_amdgcn_mfma_f32_16x16x32_bf16(af[0][ks], bf, acc[0][t], 0, 0, 0);
                acc[1][t] = __builtin_amdgcn_mfma_f32_16x16x32_bf16(af[1][ks], bf, acc[1][t], 0, 0, 0);
            }
#pragma unroll
        for (int m = 0; m < 2; ++m) {
            int nrow = nbase + m * 16 + (lane >> 4) * 4;
#pragma unroll
            for (int t = 0; t < TILES; ++t) {
                int col = t * 16 + (lane & 15);
#pragma unroll
                for (int r = 0; r < 4; ++r) {
                    float v = acc[m][t][r] + bias_t[t];
                    if (RELU) v = fmaxf(v, 0.f);
                    out[(size_t)(nrow + r) * Fout + col] = f2bf(v);
                }
            }
        }
    }
}

// ---------------- layer 3 transform via narrow MFMA: [z|r] = h2 @ B (128x16) ----------------
__global__ __launch_bounds__(256) void k_zr_mfma(const unsigned short* __restrict__ h2,
                                                 const float* __restrict__ W4l, const float* __restrict__ W4r,
                                                 float* __restrict__ z, float* __restrict__ r) {
    __shared__ short sB[4 * 64 * 8];           // 4 ks-frags
    {
        int idx = threadIdx.x;                 // 256 = 4*64 entries exactly
        int l = idx & 63;
        int ks = idx >> 6;
        int o = l & 15;
        int kbase = ks * 32 + (l >> 4) * 8;
        short8 v;
#pragma unroll
        for (int j = 0; j < 8; ++j) {
            int k = kbase + j;
            float w = 0.f;
            if (o < 3) w = W4l[o * 128 + k];
            else if (o >= 4 && o < 7) w = W4r[(o - 4) * 128 + k];
            v[j] = (short)f2bf(w);
        }
        *(short8*)&sB[idx * 8] = v;
    }
    __syncthreads();
    const int lane = threadIdx.x & 63;
    short8 bf[4];
#pragma unroll
    for (int ks = 0; ks < 4; ++ks) bf[ks] = *(const short8*)&sB[(ks * 64 + lane) * 8];

    const int col = lane & 15;
    const int rbase = (lane >> 4) * 4;
    const int wave = blockIdx.x * 4 + (threadIdx.x >> 6);
    const int nchunks = NN / 32;               // 3125
    for (int ci = wave; ci < nchunks; ci += gridDim.x * 4) {
        int nbase = ci * 32;
        const unsigned short* a0 = h2 + (size_t)(nbase + (lane & 15)) * 128 + (lane >> 4) * 8;
        f32x4 acc0 = (f32x4){0.f, 0.f, 0.f, 0.f};
        f32x4 acc1 = (f32x4){0.f, 0.f, 0.f, 0.f};
#pragma unroll
        for (int ks = 0; ks < 4; ++ks) {
            short8 af0 = *(const short8*)(a0 + ks * 32);
            short8 af1 = *(const short8*)(a0 + 16 * 128 + ks * 32);
            acc0 = __builtin_amdgcn_mfma_f32_16x16x32_bf16(af0, bf[ks], acc0, 0, 0, 0);
            acc1 = __builtin_amdgcn_mfma_f32_16x16x32_bf16(af1, bf[ks], acc1, 0, 0, 0);
        }
#pragma unroll
        for (int m = 0; m < 2; ++m) {
            f32x4 a = m ? acc1 : acc0;
            int nr = nbase + m * 16 + rbase;
            if (col < 3) {
#pragma unroll
                for (int q = 0; q < 4; ++q) z[(size_t)(nr + q) * 4 + col] = a[q];
            } else if (col >= 4 && col < 7) {
#pragma unroll
                for (int q = 0; q < 4; ++q) r[(size_t)(nr + q) * 4 + col - 4] = a[q];
            }
        }
    }
}

// ---------------- final: out = mean(z)[n] + r[n] + b4 ----------------
__global__ __launch_bounds__(256) void k_final(const float* __restrict__ z, const float* __restrict__ r,
                                               const float* __restrict__ b4,
                                               const int* __restrict__ row_start, const int* __restrict__ csr_src,
                                               const float* __restrict__ deg_inv, float* __restrict__ out) {
    int n = blockIdx.x * 256 + threadIdx.x;
    if (n >= NN) return;
    int rs = row_start[n], re = row_start[n + 1];
    float a0 = 0, a1 = 0, a2 = 0, b0 = 0, b1 = 0, b2 = 0;
    int k = rs;
    for (; k + 4 <= re; k += 4) {
        int s0 = csr_src[k], s1 = csr_src[k + 1], s2 = csr_src[k + 2], s3 = csr_src[k + 3];
        float4 z0 = *(const float4*)&z[4 * (size_t)s0];
        float4 z1 = *(const float4*)&z[4 * (size_t)s1];
        float4 z2 = *(const float4*)&z[4 * (size_t)s2];
        float4 z3 = *(const float4*)&z[4 * (size_t)s3];
        a0 += z0.x; a1 += z0.y; a2 += z0.z;
        b0 += z1.x; b1 += z1.y; b2 += z1.z;
        a0 += z2.x; a1 += z2.y; a2 += z2.z;
        b0 += z3.x; b1 += z3.y; b2 += z3.z;
    }
    for (; k < re; ++k) {
        float4 z0 = *(const float4*)&z[4 * (size_t)csr_src[k]];
        a0 += z0.x; a1 += z0.y; a2 += z0.z;
    }
    float di = deg_inv[n];
    float4 rn = *(const float4*)&r[4 * (size_t)n];
    out[(size_t)n * 3 + 0] = (a0 + b0) * di + rn.x + b4[0];
    out[(size_t)n * 3 + 1] = (a1 + b1) * di + rn.y + b4[1];
    out[(size_t)n * 3 + 2] = (a2 + b2) * di + rn.z + b4[2];
}

extern "C" void kernel_launch(void* const* d_in, const int* in_sizes, int n_in,
                              void* d_out, int out_size, void* d_ws, size_t ws_size,
                              hipStream_t stream) {
    const float* x   = (const float*)d_in[0];
    const int*   ei  = (const int*)d_in[1];
    const float* W1l = (const float*)d_in[2];
    const float* b1  = (const float*)d_in[3];
    const float* W1r = (const float*)d_in[4];
    const float* W2l = (const float*)d_in[5];
    const float* b2  = (const float*)d_in[6];
    const float* W2r = (const float*)d_in[7];
    const float* W4l = (const float*)d_in[8];
    const float* b4  = (const float*)d_in[9];
    const float* W4r = (const float*)d_in[10];
    float* out = (float*)d_out;

    char* ws = (char*)d_ws;
    size_t off = 0;
    auto alloc = [&](size_t bytes) -> void* {
        void* p = ws + off;
        off = (off + bytes + 255) & ~(size_t)255;
        return p;
    };
    int*   deg       = (int*)alloc((size_t)NN * 4);
    int*   row_start = (int*)alloc(((size_t)NN + 1) * 4);
    int*   csr_src   = (int*)alloc((size_t)EE * 4);
    float* deg_inv   = (float*)alloc((size_t)NN * 4);
    int*   bsum      = (int*)alloc((size_t)NB * 4);
    int*   boff      = (int*)alloc((size_t)NB * 4);
    int*   pcur      = (int*)alloc((size_t)NBUCKET * 4);
    unsigned short* xb    = (unsigned short*)alloc((size_t)NN * 40 * 2);
    unsigned short* meanb = (unsigned short*)alloc((size_t)NN * 64 * 2);   // 12.8 MB, reused L1+L2
    unsigned short* h1    = (unsigned short*)alloc((size_t)NN * 64 * 2);
    unsigned short* h2    = (unsigned short*)alloc((size_t)NN * 128 * 2);  // 25.6 MB
    float* zbuf = (float*)alloc((size_t)NN * 4 * 4);
    float* rbuf = (float*)alloc((size_t)NN * 4 * 4);
    // pairs (8.4 MB) aliases h2 (25.6 MB): dead before h2 first written (L2 gemm)
    unsigned int* pairs = (unsigned int*)h2;

    const int* e_src = ei;
    const int* e_dst = ei + EE;

    hipMemsetAsync(pcur, 0, (size_t)NBUCKET * 4, stream);

    // phase 1: bucket (packed, block-local reservation) + x->bf16, one dispatch
    k_bucket_cvt<<<BUCKET_BLOCKS + CVT_BLOCKS, 256, 0, stream>>>(e_src, e_dst, pcur, pairs, x, xb);
    // phase 1.5: per-range LDS degree count
    k_degr<<<NRANGE, 1024, 0, stream>>>(pairs, pcur, deg);
    k_bsum<<<NB, 256, 0, stream>>>(deg, bsum);
    k_bscan<<<1, 512, 0, stream>>>(bsum, boff, row_start);
    k_scan2<<<NB, 256, 0, stream>>>(deg, boff, row_start, deg_inv);
    // phase 2: scatter with per-range LDS cursors
    k_scatter2<<<NRANGE, 1024, 0, stream>>>(pairs, pcur, row_start, csr_src);

    const int mean_blocks = ((size_t)NN * 8 + 255) / 256;   // 3125
    const int gemm_blocks = 782;

    // layer 1: 40 -> 64
    k_meanb<40><<<mean_blocks, 256, 0, stream>>>(xb, row_start, csr_src, deg_inv, meanb);
    k_gemm<40, 64, true><<<gemm_blocks, 256, 0, stream>>>(meanb, xb, W1l, b1, W1r, h1);

    // layer 2: 64 -> 128
    k_meanb<64><<<mean_blocks, 256, 0, stream>>>(h1, row_start, csr_src, deg_inv, meanb);
    k_gemm<64, 128, true><<<gemm_blocks, 256, 0, stream>>>(meanb, h1, W2l, b2, W2r, h2);

    // layer 3: 128 -> 3, transform-before-gather (narrow MFMA)
    k_zr_mfma<<<gemm_blocks, 256, 0, stream>>>(h2, W4l, W4r, zbuf, rbuf);
    k_final<<<(NN + 255) / 256, 256, 0, stream>>>(zbuf, rbuf, b4, row_start, csr_src, deg_inv, out);
}

// Round 2
// 242.141 us; speedup vs baseline: 1.1180x; 1.1180x over previous
//
#include <hip/hip_runtime.h>
#include <hip/hip_bf16.h>

// GraphSAGE 3-layer: 40 -> 64 -> 128 -> 3, mean aggregation over fixed edges.
// R15 (on R14): CSR-build phase collapsed.
//  - NRANGE 64 -> 256 (RSIZE=391): 256 build blocks (full CU coverage),
//    4x fewer LDS-atomic collisions in bucketing.
//  - k_degr + k_bsum + k_bscan + k_scan2 + k_scatter2 fused into ONE k_build:
//    per-range block counts degrees in LDS, computes its global row base from
//    the 2KB pcur array (256-wide LDS scan), scans local degrees, writes
//    row_start/deg_inv, then scatters. deg/bsum/boff buffers eliminated.
//  - Dispatches 12 -> 9.

static constexpr int NN = 100000;
static constexpr int EE = 1600000;
static constexpr int NRANGE = 256;
static constexpr int RSIZE = (NN + NRANGE - 1) / NRANGE;   // 391
static constexpr int RPAD = 512;                           // pow2 >= RSIZE
static constexpr int NBUCKET = 8 * NRANGE;                 // 2048
static constexpr int CAP = 1024;     // per-bucket capacity (mean ~781, +8.7 sigma)
static constexpr int BCHUNK = 2048;  // edges per block (8 per thread)
static constexpr int BUCKET_BLOCKS = (EE + BCHUNK - 1) / BCHUNK;  // 782
static constexpr int CVT_BLOCKS = (NN * 40 / 8 + 255) / 256;      // 1954

typedef __attribute__((ext_vector_type(8))) short short8;
typedef __attribute__((ext_vector_type(4))) float f32x4;

__device__ __forceinline__ float bf2f(unsigned short u) {
    union { unsigned int i; float f; } c; c.i = ((unsigned int)u) << 16; return c.f;
}
__device__ __forceinline__ unsigned short f2bf(float f) {
    union { float f; unsigned int i; } c; c.f = f;
    unsigned int x = c.i;
    return (unsigned short)((x + 0x7fffu + ((x >> 16) & 1u)) >> 16);   // RNE
}

// ---------------- phase 1 (fused): bucket edges (packed) + x->bf16 convert ----------------
__global__ __launch_bounds__(256) void k_bucket_cvt(const int* __restrict__ src, const int* __restrict__ dst,
                                                    int* __restrict__ pcur, unsigned int* __restrict__ pairs,
                                                    const float* __restrict__ x, unsigned short* __restrict__ xb) {
    __shared__ int cnt[NRANGE];
    __shared__ int base[NRANGE];
    const int tid = threadIdx.x;
    if (blockIdx.x >= BUCKET_BLOCKS) {
        // ---- convert branch: fp32 -> bf16 rows of x ----
        int i = (blockIdx.x - BUCKET_BLOCKS) * 256 + tid;
        if (i < NN * 40 / 8) {
            const float4* p = (const float4*)(x + (size_t)i * 8);
            float4 a = p[0], b = p[1];
            short8 v;
            v[0] = (short)f2bf(a.x); v[1] = (short)f2bf(a.y); v[2] = (short)f2bf(a.z); v[3] = (short)f2bf(a.w);
            v[4] = (short)f2bf(b.x); v[5] = (short)f2bf(b.y); v[6] = (short)f2bf(b.z); v[7] = (short)f2bf(b.w);
            *(short8*)(xb + (size_t)i * 8) = v;
        }
        return;
    }
    // ---- bucket branch: block-local reservation, packed (s | dloc<<17) ----
    const int part = blockIdx.x & 7;            // this block's XCD tag (round-robin)
    const int e0 = blockIdx.x * BCHUNK;
    cnt[tid] = 0;                               // NRANGE == blockDim == 256
    __syncthreads();
    int r_[8], lp_[8];
    unsigned int p_[8];
#pragma unroll
    for (int j = 0; j < 8; ++j) {
        int e = e0 + j * 256 + tid;
        r_[j] = -1;
        if (e < EE) {
            int d = dst[e];
            int s = src[e];
            int r = d / RSIZE;                  // const-divide -> magic mul
            r_[j] = r;
            p_[j] = (unsigned int)s | ((unsigned int)(d - r * RSIZE) << 17);
            lp_[j] = atomicAdd(&cnt[r], 1);     // fast LDS atomic
        }
    }
    __syncthreads();
    {
        int c = cnt[tid];
        base[tid] = (c > 0) ? atomicAdd(&pcur[(part << 8) | tid], c) : 0;  // 1 global RMW / bucket / block
    }
    __syncthreads();
#pragma unroll
    for (int j = 0; j < 8; ++j) {
        if (r_[j] >= 0) {
            int pos = base[r_[j]] + lp_[j];
            if (pos < CAP) pairs[(size_t)((part << 8) | r_[j]) * CAP + pos] = p_[j];
        }
    }
}

// ---------------- fused CSR build: degree count + scan + row_start/deg_inv + scatter ----------------
// One block per range (256 blocks x 1024 threads). All phases block-local:
//   pass 1: LDS degree histogram of this range's 8 part-buckets
//   range base: sum+scan the 2KB pcur array in LDS (every block redundantly; trivial)
//   local scan: Hillis-Steele over RPAD=512
//   pass 2: scatter with LDS cursors into this range's contiguous csr segment
__global__ __launch_bounds__(1024) void k_build(const unsigned int* __restrict__ pairs,
                                                const int* __restrict__ pcur,
                                                int* __restrict__ row_start, float* __restrict__ deg_inv,
                                                int* __restrict__ csr_src) {
    __shared__ int ldeg[RPAD];
    __shared__ int lrs[RPAD];
    __shared__ int rtot[NRANGE];
    const int tid = threadIdx.x;
    const int r = blockIdx.x;
    const int lo = r * RSIZE;
    const int nloc = (lo + RSIZE <= NN) ? RSIZE : (NN - lo);
    for (int t = tid; t < RPAD; t += 1024) ldeg[t] = 0;
    __syncthreads();
    // pass 1: degree histogram
    for (int p = 0; p < 8; ++p) {
        int b = (p << 8) | r;
        int len = pcur[b]; if (len > CAP) len = CAP;
        const unsigned int* bp = pairs + (size_t)b * CAP;
        for (int i = tid; i < len; i += 1024)
            atomicAdd(&ldeg[bp[i] >> 17], 1);
    }
    // per-range totals from pcur (independent of ldeg)
    if (tid < NRANGE) {
        int s = 0;
#pragma unroll
        for (int p = 0; p < 8; ++p) {
            int c = pcur[(p << 8) | tid];
            s += (c > CAP) ? CAP : c;
        }
        rtot[tid] = s;
    }
    __syncthreads();
    // inclusive scan of rtot (256 values)
    for (int d = 1; d < NRANGE; d <<= 1) {
        int t = (tid < NRANGE && tid >= d) ? rtot[tid - d] : 0;
        __syncthreads();
        if (tid < NRANGE) rtot[tid] += t;
        __syncthreads();
    }
    const int rbase = (r == 0) ? 0 : rtot[r - 1];
    // inclusive scan of ldeg -> lrs (512 values)
    if (tid < RPAD) lrs[tid] = ldeg[tid];
    __syncthreads();
    for (int d = 1; d < RPAD; d <<= 1) {
        int t = (tid < RPAD && tid >= d) ? lrs[tid - d] : 0;
        __syncthreads();
        if (tid < RPAD) lrs[tid] += t;
        __syncthreads();
    }
    // write row_start / deg_inv; convert lrs to exclusive, reset ldeg to cursors
    int excl = 0, dg = 0;
    if (tid < RPAD) { dg = ldeg[tid]; excl = lrs[tid] - dg; }
    if (tid < nloc) {
        row_start[lo + tid] = rbase + excl;
        deg_inv[lo + tid] = (dg > 0) ? 1.0f / (float)dg : 0.0f;
    }
    if (r == 0 && tid == 0) row_start[NN] = EE;
    __syncthreads();
    if (tid < RPAD) { lrs[tid] = excl; ldeg[tid] = 0; }
    __syncthreads();
    // pass 2: scatter
    for (int p = 0; p < 8; ++p) {
        int b = (p << 8) | r;
        int len = pcur[b]; if (len > CAP) len = CAP;
        const unsigned int* bp = pairs + (size_t)b * CAP;
        for (int i = tid; i < len; i += 1024) {
            unsigned int pk = bp[i];
            int dloc = pk >> 17;
            int lp = atomicAdd(&ldeg[dloc], 1);             // LDS cursor
            csr_src[rbase + lrs[dloc] + lp] = (int)(pk & 0x1FFFFu);
        }
    }
}

// ---------------- bf16 mean-aggregate into mean buffer (NN x 64, zero-padded) ----------------
template<int Fin>
__global__ __launch_bounds__(256) void k_meanb(const unsigned short* __restrict__ xin,
                                               const int* __restrict__ row_start,
                                               const int* __restrict__ csr_src,
                                               const float* __restrict__ deg_inv,
                                               unsigned short* __restrict__ meanb) {
    constexpr int CH = Fin / 8;     // data chunks (5 or 8)
    int gid = blockIdx.x * 256 + threadIdx.x;
    int node = gid >> 3;
    int c = gid & 7;
    if (node >= NN) return;
    float acc[8] = {0, 0, 0, 0, 0, 0, 0, 0};
    if (c < CH) {
        const unsigned short* xq = xin + c * 8;
        int rs = row_start[node], re = row_start[node + 1];
        int k = rs;
        for (; k + 4 <= re; k += 4) {
            int s0 = csr_src[k], s1 = csr_src[k + 1], s2 = csr_src[k + 2], s3 = csr_src[k + 3];
            short8 v0 = *(const short8*)(xq + (size_t)s0 * Fin);
            short8 v1 = *(const short8*)(xq + (size_t)s1 * Fin);
            short8 v2 = *(const short8*)(xq + (size_t)s2 * Fin);
            short8 v3 = *(const short8*)(xq + (size_t)s3 * Fin);
#pragma unroll
            for (int j = 0; j < 8; ++j)
                acc[j] += (bf2f((unsigned short)v0[j]) + bf2f((unsigned short)v1[j]))
                        + (bf2f((unsigned short)v2[j]) + bf2f((unsigned short)v3[j]));
        }
        for (; k < re; ++k) {
            short8 v0 = *(const short8*)(xq + (size_t)csr_src[k] * Fin);
#pragma unroll
            for (int j = 0; j < 8; ++j) acc[j] += bf2f((unsigned short)v0[j]);
        }
        float di = deg_inv[node];
#pragma unroll
        for (int j = 0; j < 8; ++j) acc[j] *= di;
    }
    short8 m;
#pragma unroll
    for (int j = 0; j < 8; ++j) m[j] = (c < CH) ? (short)f2bf(acc[j]) : (short)0;
    *(short8*)(meanb + (size_t)node * 64 + c * 8) = m;
}

// ---------------- MFMA GEMM: out = relu?(mean@Wl^T + root@Wr^T + b) ----------------
// K = 128 (mean 64-padded | root 64-padded); root read DIRECTLY from xb/h1
// (stride Fin), zero chunks where k >= Fin. B frags: k<64 -> Wl, else Wr.
template<int Fin, int Fout, bool RELU>
__global__ __launch_bounds__(256) void k_gemm(const unsigned short* __restrict__ meanb,
                                              const unsigned short* __restrict__ root,
                                              const float* __restrict__ Wl,
                                              const float* __restrict__ bias,
                                              const float* __restrict__ Wr,
                                              unsigned short* __restrict__ out) {
    constexpr int KS = 4;                       // 2 mean + 2 root
    constexpr int TILES = Fout / 16;
    __shared__ short sB[TILES * KS * 64 * 8];
    const int lane = threadIdx.x & 63;
    for (int idx = threadIdx.x; idx < TILES * KS * 64; idx += 256) {
        int l = idx & 63;
        int ks = (idx >> 6) % KS;
        int t = idx / (64 * KS);
        int o = t * 16 + (l & 15);
        int kbase = ks * 32 + (l >> 4) * 8;
        short8 v;
#pragma unroll
        for (int j = 0; j < 8; ++j) {
            int k = kbase + j;
            float w;
            if (k < 64) w = (k < Fin) ? Wl[(size_t)o * Fin + k] : 0.f;
            else { int k2 = k - 64; w = (k2 < Fin) ? Wr[(size_t)o * Fin + k2] : 0.f; }
            v[j] = (short)f2bf(w);
        }
        *(short8*)&sB[idx * 8] = v;
    }
    __syncthreads();
    float bias_t[TILES];
#pragma unroll
    for (int t = 0; t < TILES; ++t) bias_t[t] = bias[t * 16 + (lane & 15)];

    const int kchunk = (lane >> 4) * 8;         // 0,8,16,24 within a 32-wide ks step
    const int wave = blockIdx.x * 4 + (threadIdx.x >> 6);
    const int nchunks = NN / 32;                // 3125
    for (int ci = wave; ci < nchunks; ci += gridDim.x * 4) {
        int nbase = ci * 32;
        int row0 = nbase + (lane & 15);
        const unsigned short* m0 = meanb + (size_t)row0 * 64 + kchunk;
        const unsigned short* r0 = root + (size_t)row0 * Fin + kchunk;
        short8 af[2][KS];
#pragma unroll
        for (int ks = 0; ks < 2; ++ks) {        // mean halves (always valid: 64-padded)
            af[0][ks] = *(const short8*)(m0 + ks * 32);
            af[1][ks] = *(const short8*)(m0 + 16 * 64 + ks * 32);
        }
#pragma unroll
        for (int ks = 0; ks < 2; ++ks) {        // root halves (guard k >= Fin chunks)
            int k2 = ks * 32 + kchunk;
            if (k2 + 8 <= Fin) {
                af[0][2 + ks] = *(const short8*)(r0 + ks * 32);
                af[1][2 + ks] = *(const short8*)(r0 + (size_t)16 * Fin + ks * 32);
            } else {
                short8 zz = {0, 0, 0, 0, 0, 0, 0, 0};
                af[0][2 + ks] = zz;
                af[1][2 + ks] = zz;
            }
        }
        f32x4 acc[2][TILES];
#pragma unroll
        for (int m = 0; m < 2; ++m)
#pragma unroll
            for (int t = 0; t < TILES; ++t) acc[m][t] = (f32x4){0.f, 0.f, 0.f, 0.f};
#pragma unroll
        for (int t = 0; t < TILES; ++t)
#pragma unroll
            for (int ks = 0; ks < KS; ++ks) {
                short8 bf = *(const short8*)&sB[((t * KS + ks) * 64 + lane) * 8];
                acc[0][t] = __builtin_amdgcn_mfma_f32_16x16x32_bf16(af[0][ks], bf, acc[0][t], 0, 0, 0);
                acc[1][t] = __builtin_amdgcn_mfma_f32_16x16x32_bf16(af[1][ks], bf, acc[1][t], 0, 0, 0);
            }
#pragma unroll
        for (int m = 0; m < 2; ++m) {
            int nrow = nbase + m * 16 + (lane >> 4) * 4;
#pragma unroll
            for (int t = 0; t < TILES; ++t) {
                int col = t * 16 + (lane & 15);
#pragma unroll
                for (int r = 0; r < 4; ++r) {
                    float v = acc[m][t][r] + bias_t[t];
                    if (RELU) v = fmaxf(v, 0.f);
                    out[(size_t)(nrow + r) * Fout + col] = f2bf(v);
                }
            }
        }
    }
}

// ---------------- layer 3 transform via narrow MFMA: [z|r] = h2 @ B (128x16) ----------------
__global__ __launch_bounds__(256) void k_zr_mfma(const unsigned short* __restrict__ h2,
                                                 const float* __restrict__ W4l, const float* __restrict__ W4r,
                                                 float* __restrict__ z, float* __restrict__ r) {
    __shared__ short sB[4 * 64 * 8];           // 4 ks-frags
    {
        int idx = threadIdx.x;                 // 256 = 4*64 entries exactly
        int l = idx & 63;
        int ks = idx >> 6;
        int o = l & 15;
        int kbase = ks * 32 + (l >> 4) * 8;
        short8 v;
#pragma unroll
        for (int j = 0; j < 8; ++j) {
            int k = kbase + j;
            float w = 0.f;
            if (o < 3) w = W4l[o * 128 + k];
            else if (o >= 4 && o < 7) w = W4r[(o - 4) * 128 + k];
            v[j] = (short)f2bf(w);
        }
        *(short8*)&sB[idx * 8] = v;
    }
    __syncthreads();
    const int lane = threadIdx.x & 63;
    short8 bf[4];
#pragma unroll
    for (int ks = 0; ks < 4; ++ks) bf[ks] = *(const short8*)&sB[(ks * 64 + lane) * 8];

    const int col = lane & 15;
    const int rbase = (lane >> 4) * 4;
    const int wave = blockIdx.x * 4 + (threadIdx.x >> 6);
    const int nchunks = NN / 32;               // 3125
    for (int ci = wave; ci < nchunks; ci += gridDim.x * 4) {
        int nbase = ci * 32;
        const unsigned short* a0 = h2 + (size_t)(nbase + (lane & 15)) * 128 + (lane >> 4) * 8;
        f32x4 acc0 = (f32x4){0.f, 0.f, 0.f, 0.f};
        f32x4 acc1 = (f32x4){0.f, 0.f, 0.f, 0.f};
#pragma unroll
        for (int ks = 0; ks < 4; ++ks) {
            short8 af0 = *(const short8*)(a0 + ks * 32);
            short8 af1 = *(const short8*)(a0 + 16 * 128 + ks * 32);
            acc0 = __builtin_amdgcn_mfma_f32_16x16x32_bf16(af0, bf[ks], acc0, 0, 0, 0);
            acc1 = __builtin_amdgcn_mfma_f32_16x16x32_bf16(af1, bf[ks], acc1, 0, 0, 0);
        }
#pragma unroll
        for (int m = 0; m < 2; ++m) {
            f32x4 a = m ? acc1 : acc0;
            int nr = nbase + m * 16 + rbase;
            if (col < 3) {
#pragma unroll
                for (int q = 0; q < 4; ++q) z[(size_t)(nr + q) * 4 + col] = a[q];
            } else if (col >= 4 && col < 7) {
#pragma unroll
                for (int q = 0; q < 4; ++q) r[(size_t)(nr + q) * 4 + col - 4] = a[q];
            }
        }
    }
}

// ---------------- final: out = mean(z)[n] + r[n] + b4 ----------------
__global__ __launch_bounds__(256) void k_final(const float* __restrict__ z, const float* __restrict__ r,
                                               const float* __restrict__ b4,
                                               const int* __restrict__ row_start, const int* __restrict__ csr_src,
                                               const float* __restrict__ deg_inv, float* __restrict__ out) {
    int n = blockIdx.x * 256 + threadIdx.x;
    if (n >= NN) return;
    int rs = row_start[n], re = row_start[n + 1];
    float a0 = 0, a1 = 0, a2 = 0, b0 = 0, b1 = 0, b2 = 0;
    int k = rs;
    for (; k + 4 <= re; k += 4) {
        int s0 = csr_src[k], s1 = csr_src[k + 1], s2 = csr_src[k + 2], s3 = csr_src[k + 3];
        float4 z0 = *(const float4*)&z[4 * (size_t)s0];
        float4 z1 = *(const float4*)&z[4 * (size_t)s1];
        float4 z2 = *(const float4*)&z[4 * (size_t)s2];
        float4 z3 = *(const float4*)&z[4 * (size_t)s3];
        a0 += z0.x; a1 += z0.y; a2 += z0.z;
        b0 += z1.x; b1 += z1.y; b2 += z1.z;
        a0 += z2.x; a1 += z2.y; a2 += z2.z;
        b0 += z3.x; b1 += z3.y; b2 += z3.z;
    }
    for (; k < re; ++k) {
        float4 z0 = *(const float4*)&z[4 * (size_t)csr_src[k]];
        a0 += z0.x; a1 += z0.y; a2 += z0.z;
    }
    float di = deg_inv[n];
    float4 rn = *(const float4*)&r[4 * (size_t)n];
    out[(size_t)n * 3 + 0] = (a0 + b0) * di + rn.x + b4[0];
    out[(size_t)n * 3 + 1] = (a1 + b1) * di + rn.y + b4[1];
    out[(size_t)n * 3 + 2] = (a2 + b2) * di + rn.z + b4[2];
}

extern "C" void kernel_launch(void* const* d_in, const int* in_sizes, int n_in,
                              void* d_out, int out_size, void* d_ws, size_t ws_size,
                              hipStream_t stream) {
    const float* x   = (const float*)d_in[0];
    const int*   ei  = (const int*)d_in[1];
    const float* W1l = (const float*)d_in[2];
    const float* b1  = (const float*)d_in[3];
    const float* W1r = (const float*)d_in[4];
    const float* W2l = (const float*)d_in[5];
    const float* b2  = (const float*)d_in[6];
    const float* W2r = (const float*)d_in[7];
    const float* W4l = (const float*)d_in[8];
    const float* b4  = (const float*)d_in[9];
    const float* W4r = (const float*)d_in[10];
    float* out = (float*)d_out;

    char* ws = (char*)d_ws;
    size_t off = 0;
    auto alloc = [&](size_t bytes) -> void* {
        void* p = ws + off;
        off = (off + bytes + 255) & ~(size_t)255;
        return p;
    };
    int*   row_start = (int*)alloc(((size_t)NN + 1) * 4);
    int*   csr_src   = (int*)alloc((size_t)EE * 4);
    float* deg_inv   = (float*)alloc((size_t)NN * 4);
    int*   pcur      = (int*)alloc((size_t)NBUCKET * 4);
    unsigned short* xb    = (unsigned short*)alloc((size_t)NN * 40 * 2);
    unsigned short* meanb = (unsigned short*)alloc((size_t)NN * 64 * 2);   // 12.8 MB, reused L1+L2
    unsigned short* h1    = (unsigned short*)alloc((size_t)NN * 64 * 2);
    unsigned short* h2    = (unsigned short*)alloc((size_t)NN * 128 * 2);  // 25.6 MB
    float* zbuf = (float*)alloc((size_t)NN * 4 * 4);
    float* rbuf = (float*)alloc((size_t)NN * 4 * 4);
    // pairs (8.4 MB) aliases h2 (25.6 MB): dead before h2 first written (L2 gemm)
    unsigned int* pairs = (unsigned int*)h2;

    const int* e_src = ei;
    const int* e_dst = ei + EE;

    hipMemsetAsync(pcur, 0, (size_t)NBUCKET * 4, stream);

    // phase 1: bucket (packed, block-local reservation) + x->bf16, one dispatch
    k_bucket_cvt<<<BUCKET_BLOCKS + CVT_BLOCKS, 256, 0, stream>>>(e_src, e_dst, pcur, pairs, x, xb);
    // phase 2: fused degree + scan + row_start/deg_inv + scatter
    k_build<<<NRANGE, 1024, 0, stream>>>(pairs, pcur, row_start, deg_inv, csr_src);

    const int mean_blocks = ((size_t)NN * 8 + 255) / 256;   // 3125
    const int gemm_blocks = 782;

    // layer 1: 40 -> 64
    k_meanb<40><<<mean_blocks, 256, 0, stream>>>(xb, row_start, csr_src, deg_inv, meanb);
    k_gemm<40, 64, true><<<gemm_blocks, 256, 0, stream>>>(meanb, xb, W1l, b1, W1r, h1);

    // layer 2: 64 -> 128
    k_meanb<64><<<mean_blocks, 256, 0, stream>>>(h1, row_start, csr_src, deg_inv, meanb);
    k_gemm<64, 128, true><<<gemm_blocks, 256, 0, stream>>>(meanb, h1, W2l, b2, W2r, h2);

    // layer 3: 128 -> 3, transform-before-gather (narrow MFMA)
    k_zr_mfma<<<gemm_blocks, 256, 0, stream>>>(h2, W4l, W4r, zbuf, rbuf);
    k_final<<<(NN + 255) / 256, 256, 0, stream>>>(zbuf, rbuf, b4, row_start, csr_src, deg_inv, out);
}

// Round 3
// 226.558 us; speedup vs baseline: 1.1949x; 1.0688x over previous
//
#include <hip/hip_runtime.h>
#include <hip/hip_bf16.h>

// GraphSAGE 3-layer: 40 -> 64 -> 128 -> 3, mean aggregation over fixed edges.
// R16 (on R15): layer fusion.
//  - k_meanb fused into k_gemm -> k_fused: per 32-node chunk, phase A
//    gather-aggregates the mean tile into LDS (padded [32][72] bf16, never
//    hits global), phase B MFMAs it against register-resident weight frags.
//    meanb buffer eliminated (51 MB round-trip saved).
//  - k_zr_mfma fused into layer-2 epilogue: h2 tile (relu'd bf16) goes to
//    LDS [32][136], waves 0-1 run the narrow K=128 MFMA and write z/r
//    directly. h2 buffer eliminated (51 MB round-trip saved).
//  - Weight B-frags live in registers (old LDS read was 8-way bank conflict).
//  - Dispatches 9 -> 6.

static constexpr int NN = 100000;
static constexpr int EE = 1600000;
static constexpr int NRANGE = 256;
static constexpr int RSIZE = (NN + NRANGE - 1) / NRANGE;   // 391
static constexpr int RPAD = 512;                           // pow2 >= RSIZE
static constexpr int NBUCKET = 8 * NRANGE;                 // 2048
static constexpr int CAP = 1024;     // per-bucket capacity (mean ~781, +8.7 sigma)
static constexpr int BCHUNK = 2048;  // edges per block (8 per thread)
static constexpr int BUCKET_BLOCKS = (EE + BCHUNK - 1) / BCHUNK;  // 782
static constexpr int CVT_BLOCKS = (NN * 40 / 8 + 255) / 256;      // 1954
static constexpr int NCHUNK = NN / 32;                            // 3125 exact

typedef __attribute__((ext_vector_type(8))) short short8;
typedef __attribute__((ext_vector_type(4))) float f32x4;

__device__ __forceinline__ float bf2f(unsigned short u) {
    union { unsigned int i; float f; } c; c.i = ((unsigned int)u) << 16; return c.f;
}
__device__ __forceinline__ unsigned short f2bf(float f) {
    union { float f; unsigned int i; } c; c.f = f;
    unsigned int x = c.i;
    return (unsigned short)((x + 0x7fffu + ((x >> 16) & 1u)) >> 16);   // RNE
}

// ---------------- phase 1 (fused): bucket edges (packed) + x->bf16 convert ----------------
__global__ __launch_bounds__(256) void k_bucket_cvt(const int* __restrict__ src, const int* __restrict__ dst,
                                                    int* __restrict__ pcur, unsigned int* __restrict__ pairs,
                                                    const float* __restrict__ x, unsigned short* __restrict__ xb) {
    __shared__ int cnt[NRANGE];
    __shared__ int base[NRANGE];
    const int tid = threadIdx.x;
    if (blockIdx.x >= BUCKET_BLOCKS) {
        // ---- convert branch: fp32 -> bf16 rows of x ----
        int i = (blockIdx.x - BUCKET_BLOCKS) * 256 + tid;
        if (i < NN * 40 / 8) {
            const float4* p = (const float4*)(x + (size_t)i * 8);
            float4 a = p[0], b = p[1];
            short8 v;
            v[0] = (short)f2bf(a.x); v[1] = (short)f2bf(a.y); v[2] = (short)f2bf(a.z); v[3] = (short)f2bf(a.w);
            v[4] = (short)f2bf(b.x); v[5] = (short)f2bf(b.y); v[6] = (short)f2bf(b.z); v[7] = (short)f2bf(b.w);
            *(short8*)(xb + (size_t)i * 8) = v;
        }
        return;
    }
    // ---- bucket branch: block-local reservation, packed (s | dloc<<17) ----
    const int part = blockIdx.x & 7;            // this block's XCD tag (round-robin)
    const int e0 = blockIdx.x * BCHUNK;
    cnt[tid] = 0;                               // NRANGE == blockDim == 256
    __syncthreads();
    int r_[8], lp_[8];
    unsigned int p_[8];
#pragma unroll
    for (int j = 0; j < 8; ++j) {
        int e = e0 + j * 256 + tid;
        r_[j] = -1;
        if (e < EE) {
            int d = dst[e];
            int s = src[e];
            int r = d / RSIZE;                  // const-divide -> magic mul
            r_[j] = r;
            p_[j] = (unsigned int)s | ((unsigned int)(d - r * RSIZE) << 17);
            lp_[j] = atomicAdd(&cnt[r], 1);     // fast LDS atomic
        }
    }
    __syncthreads();
    {
        int c = cnt[tid];
        base[tid] = (c > 0) ? atomicAdd(&pcur[(part << 8) | tid], c) : 0;  // 1 global RMW / bucket / block
    }
    __syncthreads();
#pragma unroll
    for (int j = 0; j < 8; ++j) {
        if (r_[j] >= 0) {
            int pos = base[r_[j]] + lp_[j];
            if (pos < CAP) pairs[(size_t)((part << 8) | r_[j]) * CAP + pos] = p_[j];
        }
    }
}

// ---------------- fused CSR build: degree count + scan + row_start/deg_inv + scatter ----------------
__global__ __launch_bounds__(1024) void k_build(const unsigned int* __restrict__ pairs,
                                                const int* __restrict__ pcur,
                                                int* __restrict__ row_start, float* __restrict__ deg_inv,
                                                int* __restrict__ csr_src) {
    __shared__ int ldeg[RPAD];
    __shared__ int lrs[RPAD];
    __shared__ int rtot[NRANGE];
    const int tid = threadIdx.x;
    const int r = blockIdx.x;
    const int lo = r * RSIZE;
    const int nloc = (lo + RSIZE <= NN) ? RSIZE : (NN - lo);
    for (int t = tid; t < RPAD; t += 1024) ldeg[t] = 0;
    __syncthreads();
    // pass 1: degree histogram
    for (int p = 0; p < 8; ++p) {
        int b = (p << 8) | r;
        int len = pcur[b]; if (len > CAP) len = CAP;
        const unsigned int* bp = pairs + (size_t)b * CAP;
        for (int i = tid; i < len; i += 1024)
            atomicAdd(&ldeg[bp[i] >> 17], 1);
    }
    // per-range totals from pcur (independent of ldeg)
    if (tid < NRANGE) {
        int s = 0;
#pragma unroll
        for (int p = 0; p < 8; ++p) {
            int c = pcur[(p << 8) | tid];
            s += (c > CAP) ? CAP : c;
        }
        rtot[tid] = s;
    }
    __syncthreads();
    // inclusive scan of rtot (256 values)
    for (int d = 1; d < NRANGE; d <<= 1) {
        int t = (tid < NRANGE && tid >= d) ? rtot[tid - d] : 0;
        __syncthreads();
        if (tid < NRANGE) rtot[tid] += t;
        __syncthreads();
    }
    const int rbase = (r == 0) ? 0 : rtot[r - 1];
    // inclusive scan of ldeg -> lrs (512 values)
    if (tid < RPAD) lrs[tid] = ldeg[tid];
    __syncthreads();
    for (int d = 1; d < RPAD; d <<= 1) {
        int t = (tid < RPAD && tid >= d) ? lrs[tid - d] : 0;
        __syncthreads();
        if (tid < RPAD) lrs[tid] += t;
        __syncthreads();
    }
    // write row_start / deg_inv; convert lrs to exclusive, reset ldeg to cursors
    int excl = 0, dg = 0;
    if (tid < RPAD) { dg = ldeg[tid]; excl = lrs[tid] - dg; }
    if (tid < nloc) {
        row_start[lo + tid] = rbase + excl;
        deg_inv[lo + tid] = (dg > 0) ? 1.0f / (float)dg : 0.0f;
    }
    if (r == 0 && tid == 0) row_start[NN] = EE;
    __syncthreads();
    if (tid < RPAD) { lrs[tid] = excl; ldeg[tid] = 0; }
    __syncthreads();
    // pass 2: scatter
    for (int p = 0; p < 8; ++p) {
        int b = (p << 8) | r;
        int len = pcur[b]; if (len > CAP) len = CAP;
        const unsigned int* bp = pairs + (size_t)b * CAP;
        for (int i = tid; i < len; i += 1024) {
            unsigned int pk = bp[i];
            int dloc = pk >> 17;
            int lp = atomicAdd(&ldeg[dloc], 1);             // LDS cursor
            csr_src[rbase + lrs[dloc] + lp] = (int)(pk & 0x1FFFFu);
        }
    }
}

// ---------------- fused layer: gather-mean (LDS) + MFMA GEMM [+ zr epilogue] ----------------
// Per 32-node chunk:
//   phase A: thread (node=tid>>3, c=tid&7) aggregates mean chunk (fp32) and
//            stages mean+root bf16 tiles in LDS (padded [32][72], 2-way max).
//   phase B: 4 waves; wave w owns output tiles [w*TPW, w*TPW+TPW).
//            A-frags from LDS, B-frags in registers. K=128: ks 0-1 mean, 2-3 root.
//   ZR epilogue (layer 2): relu'd h2 tile -> LDS [32][136]; waves 0-1 run the
//            narrow K=128 MFMA vs W4 frags and write z/r. No h2 global buffer.
template<int Fin, int Fout, bool RELU, bool ZR>
__global__ __launch_bounds__(256) void k_fused(const unsigned short* __restrict__ xin,
                                               const int* __restrict__ row_start,
                                               const int* __restrict__ csr_src,
                                               const float* __restrict__ deg_inv,
                                               const float* __restrict__ Wl,
                                               const float* __restrict__ bias,
                                               const float* __restrict__ Wr,
                                               unsigned short* __restrict__ out,
                                               const float* __restrict__ W4l,
                                               const float* __restrict__ W4r,
                                               float* __restrict__ z,
                                               float* __restrict__ rr_) {
    constexpr int KS = 4;
    constexpr int TILES = Fout / 16;
    constexpr int TPW = TILES / 4;              // tiles per wave
    constexpr int WB = TILES * KS * 64 * 8;     // weight-fill shorts
    constexpr int SMEAN = 0;                    // [32][72]
    constexpr int SROOT = 32 * 72;              // [32][72]
    constexpr int SH2 = 2 * 32 * 72;            // [32][136] (ZR only)
    constexpr int STEADY = 2 * 32 * 72 + (ZR ? 32 * 136 : 0);
    constexpr int FILL = WB + (ZR ? 4 * 64 * 8 : 0);
    constexpr int SHM = (STEADY > FILL) ? STEADY : FILL;
    __shared__ short shm[SHM];
    const int tid = threadIdx.x;
    const int lane = tid & 63;
    const int wv = tid >> 6;

    // ---- one-time: weight frags -> LDS staging -> registers ----
    for (int idx = tid; idx < TILES * KS * 64; idx += 256) {
        int l = idx & 63;
        int ks = (idx >> 6) % KS;
        int t = idx / (64 * KS);
        int o = t * 16 + (l & 15);
        int kbase = ks * 32 + (l >> 4) * 8;
        short8 v;
#pragma unroll
        for (int j = 0; j < 8; ++j) {
            int k = kbase + j;
            float w;
            if (k < 64) w = (k < Fin) ? Wl[(size_t)o * Fin + k] : 0.f;
            else { int k2 = k - 64; w = (k2 < Fin) ? Wr[(size_t)o * Fin + k2] : 0.f; }
            v[j] = (short)f2bf(w);
        }
        *(short8*)&shm[idx * 8] = v;
    }
    if constexpr (ZR) {
        for (int idx = tid; idx < 4 * 64; idx += 256) {
            int l = idx & 63;
            int ks = idx >> 6;
            int o = l & 15;
            int kbase = ks * 32 + (l >> 4) * 8;
            short8 v;
#pragma unroll
            for (int j = 0; j < 8; ++j) {
                int k = kbase + j;
                float w = 0.f;
                if (o < 3) w = W4l[o * 128 + k];
                else if (o >= 4 && o < 7) w = W4r[(o - 4) * 128 + k];
                v[j] = (short)f2bf(w);
            }
            *(short8*)&shm[WB + idx * 8] = v;
        }
    }
    __syncthreads();
    short8 bfr[TPW][KS];
#pragma unroll
    for (int tt = 0; tt < TPW; ++tt)
#pragma unroll
        for (int ks = 0; ks < KS; ++ks)
            bfr[tt][ks] = *(const short8*)&shm[(((wv * TPW + tt) * KS + ks) * 64 + lane) * 8];
    short8 b4r[4];
    if constexpr (ZR) {
        if (wv < 2) {
#pragma unroll
            for (int ks = 0; ks < 4; ++ks)
                b4r[ks] = *(const short8*)&shm[WB + (ks * 64 + lane) * 8];
        }
    }
    float bias_t[TPW];
#pragma unroll
    for (int tt = 0; tt < TPW; ++tt) bias_t[tt] = bias[(wv * TPW + tt) * 16 + (lane & 15)];
    __syncthreads();                            // before shm reuse

    const int node8 = tid >> 3;                 // 0..31
    const int c = tid & 7;

    for (int ci = blockIdx.x; ci < NCHUNK; ci += gridDim.x) {
        const int nbase = ci * 32;
        // ---- phase A: gather-mean + root staging ----
        {
            const int node = nbase + node8;
            float acc[8] = {0, 0, 0, 0, 0, 0, 0, 0};
            short8 rv = {0, 0, 0, 0, 0, 0, 0, 0};
            if (c * 8 < Fin) {
                const unsigned short* xq = xin + c * 8;
                int rs = row_start[node], re = row_start[node + 1];
                int k = rs;
                for (; k + 4 <= re; k += 4) {
                    int s0 = csr_src[k], s1 = csr_src[k + 1], s2 = csr_src[k + 2], s3 = csr_src[k + 3];
                    short8 v0 = *(const short8*)(xq + (size_t)s0 * Fin);
                    short8 v1 = *(const short8*)(xq + (size_t)s1 * Fin);
                    short8 v2 = *(const short8*)(xq + (size_t)s2 * Fin);
                    short8 v3 = *(const short8*)(xq + (size_t)s3 * Fin);
#pragma unroll
                    for (int j = 0; j < 8; ++j)
                        acc[j] += (bf2f((unsigned short)v0[j]) + bf2f((unsigned short)v1[j]))
                                + (bf2f((unsigned short)v2[j]) + bf2f((unsigned short)v3[j]));
                }
                for (; k < re; ++k) {
                    short8 v0 = *(const short8*)(xq + (size_t)csr_src[k] * Fin);
#pragma unroll
                    for (int j = 0; j < 8; ++j) acc[j] += bf2f((unsigned short)v0[j]);
                }
                float di = deg_inv[node];
#pragma unroll
                for (int j = 0; j < 8; ++j) acc[j] *= di;
                rv = *(const short8*)(xin + (size_t)node * Fin + c * 8);
            }
            short8 mv;
#pragma unroll
            for (int j = 0; j < 8; ++j) mv[j] = (c * 8 < Fin) ? (short)f2bf(acc[j]) : (short)0;
            *(short8*)&shm[SMEAN + node8 * 72 + c * 8] = mv;
            *(short8*)&shm[SROOT + node8 * 72 + c * 8] = rv;
        }
        __syncthreads();
        // ---- phase B: MFMA ----
        short8 af[2][KS];
#pragma unroll
        for (int ks = 0; ks < KS; ++ks) {
            const int base = (ks < 2) ? SMEAN : SROOT;
            const int g = (ks & 1) * 4 + (lane >> 4);
            af[0][ks] = *(const short8*)&shm[base + (lane & 15) * 72 + g * 8];
            af[1][ks] = *(const short8*)&shm[base + (16 + (lane & 15)) * 72 + g * 8];
        }
        f32x4 acc2[2][TPW];
#pragma unroll
        for (int m = 0; m < 2; ++m)
#pragma unroll
            for (int tt = 0; tt < TPW; ++tt) acc2[m][tt] = (f32x4){0.f, 0.f, 0.f, 0.f};
#pragma unroll
        for (int tt = 0; tt < TPW; ++tt)
#pragma unroll
            for (int ks = 0; ks < KS; ++ks) {
                acc2[0][tt] = __builtin_amdgcn_mfma_f32_16x16x32_bf16(af[0][ks], bfr[tt][ks], acc2[0][tt], 0, 0, 0);
                acc2[1][tt] = __builtin_amdgcn_mfma_f32_16x16x32_bf16(af[1][ks], bfr[tt][ks], acc2[1][tt], 0, 0, 0);
            }
        if constexpr (!ZR) {
#pragma unroll
            for (int m = 0; m < 2; ++m) {
                int nrow = nbase + m * 16 + (lane >> 4) * 4;
#pragma unroll
                for (int tt = 0; tt < TPW; ++tt) {
                    int col = (wv * TPW + tt) * 16 + (lane & 15);
#pragma unroll
                    for (int q = 0; q < 4; ++q) {
                        float v = acc2[m][tt][q] + bias_t[tt];
                        if (RELU) v = fmaxf(v, 0.f);
                        out[(size_t)(nrow + q) * Fout + col] = f2bf(v);
                    }
                }
            }
        } else {
            // relu'd h2 tile -> LDS
#pragma unroll
            for (int m = 0; m < 2; ++m) {
                int row0 = m * 16 + (lane >> 4) * 4;
#pragma unroll
                for (int tt = 0; tt < TPW; ++tt) {
                    int col = (wv * TPW + tt) * 16 + (lane & 15);
#pragma unroll
                    for (int q = 0; q < 4; ++q) {
                        float v = acc2[m][tt][q] + bias_t[tt];
                        if (RELU) v = fmaxf(v, 0.f);
                        shm[SH2 + (row0 + q) * 136 + col] = (short)f2bf(v);
                    }
                }
            }
            __syncthreads();
            if (wv < 2) {
                const int row = wv * 16 + (lane & 15);
                f32x4 az = (f32x4){0.f, 0.f, 0.f, 0.f};
#pragma unroll
                for (int ks = 0; ks < 4; ++ks) {
                    short8 a4 = *(const short8*)&shm[SH2 + row * 136 + (ks * 4 + (lane >> 4)) * 8];
                    az = __builtin_amdgcn_mfma_f32_16x16x32_bf16(a4, b4r[ks], az, 0, 0, 0);
                }
                const int col = lane & 15;
                const int nr = nbase + wv * 16 + (lane >> 4) * 4;
                if (col < 3) {
#pragma unroll
                    for (int q = 0; q < 4; ++q) z[(size_t)(nr + q) * 4 + col] = az[q];
                } else if (col >= 4 && col < 7) {
#pragma unroll
                    for (int q = 0; q < 4; ++q) rr_[(size_t)(nr + q) * 4 + col - 4] = az[q];
                }
            }
        }
        __syncthreads();                        // protect shm reuse next chunk
    }
}

// ---------------- final: out = mean(z)[n] + r[n] + b4 ----------------
__global__ __launch_bounds__(256) void k_final(const float* __restrict__ z, const float* __restrict__ r,
                                               const float* __restrict__ b4,
                                               const int* __restrict__ row_start, const int* __restrict__ csr_src,
                                               const float* __restrict__ deg_inv, float* __restrict__ out) {
    int n = blockIdx.x * 256 + threadIdx.x;
    if (n >= NN) return;
    int rs = row_start[n], re = row_start[n + 1];
    float a0 = 0, a1 = 0, a2 = 0, b0 = 0, b1 = 0, b2 = 0;
    int k = rs;
    for (; k + 4 <= re; k += 4) {
        int s0 = csr_src[k], s1 = csr_src[k + 1], s2 = csr_src[k + 2], s3 = csr_src[k + 3];
        float4 z0 = *(const float4*)&z[4 * (size_t)s0];
        float4 z1 = *(const float4*)&z[4 * (size_t)s1];
        float4 z2 = *(const float4*)&z[4 * (size_t)s2];
        float4 z3 = *(const float4*)&z[4 * (size_t)s3];
        a0 += z0.x; a1 += z0.y; a2 += z0.z;
        b0 += z1.x; b1 += z1.y; b2 += z1.z;
        a0 += z2.x; a1 += z2.y; a2 += z2.z;
        b0 += z3.x; b1 += z3.y; b2 += z3.z;
    }
    for (; k < re; ++k) {
        float4 z0 = *(const float4*)&z[4 * (size_t)csr_src[k]];
        a0 += z0.x; a1 += z0.y; a2 += z0.z;
    }
    float di = deg_inv[n];
    float4 rn = *(const float4*)&r[4 * (size_t)n];
    out[(size_t)n * 3 + 0] = (a0 + b0) * di + rn.x + b4[0];
    out[(size_t)n * 3 + 1] = (a1 + b1) * di + rn.y + b4[1];
    out[(size_t)n * 3 + 2] = (a2 + b2) * di + rn.z + b4[2];
}

extern "C" void kernel_launch(void* const* d_in, const int* in_sizes, int n_in,
                              void* d_out, int out_size, void* d_ws, size_t ws_size,
                              hipStream_t stream) {
    const float* x   = (const float*)d_in[0];
    const int*   ei  = (const int*)d_in[1];
    const float* W1l = (const float*)d_in[2];
    const float* b1  = (const float*)d_in[3];
    const float* W1r = (const float*)d_in[4];
    const float* W2l = (const float*)d_in[5];
    const float* b2  = (const float*)d_in[6];
    const float* W2r = (const float*)d_in[7];
    const float* W4l = (const float*)d_in[8];
    const float* b4  = (const float*)d_in[9];
    const float* W4r = (const float*)d_in[10];
    float* out = (float*)d_out;

    char* ws = (char*)d_ws;
    size_t off = 0;
    auto alloc = [&](size_t bytes) -> void* {
        void* p = ws + off;
        off = (off + bytes + 255) & ~(size_t)255;
        return p;
    };
    int*   row_start = (int*)alloc(((size_t)NN + 1) * 4);
    int*   csr_src   = (int*)alloc((size_t)EE * 4);
    float* deg_inv   = (float*)alloc((size_t)NN * 4);
    int*   pcur      = (int*)alloc((size_t)NBUCKET * 4);
    unsigned short* xb = (unsigned short*)alloc((size_t)NN * 40 * 2);
    unsigned short* h1 = (unsigned short*)alloc((size_t)NN * 64 * 2);
    float* zbuf = (float*)alloc((size_t)NN * 4 * 4);
    float* rbuf = (float*)alloc((size_t)NN * 4 * 4);
    unsigned int* pairs = (unsigned int*)alloc((size_t)NBUCKET * CAP * 4);   // 8.4 MB

    const int* e_src = ei;
    const int* e_dst = ei + EE;

    hipMemsetAsync(pcur, 0, (size_t)NBUCKET * 4, stream);

    // phase 1: bucket (packed, block-local reservation) + x->bf16, one dispatch
    k_bucket_cvt<<<BUCKET_BLOCKS + CVT_BLOCKS, 256, 0, stream>>>(e_src, e_dst, pcur, pairs, x, xb);
    // phase 2: fused degree + scan + row_start/deg_inv + scatter
    k_build<<<NRANGE, 1024, 0, stream>>>(pairs, pcur, row_start, deg_inv, csr_src);

    // layer 1: 40 -> 64 (fused gather + gemm)
    k_fused<40, 64, true, false><<<782, 256, 0, stream>>>(xb, row_start, csr_src, deg_inv,
                                                          W1l, b1, W1r, h1,
                                                          nullptr, nullptr, nullptr, nullptr);
    // layer 2+3a: 64 -> 128 (fused gather + gemm + zr transform)
    k_fused<64, 128, true, true><<<782, 256, 0, stream>>>(h1, row_start, csr_src, deg_inv,
                                                          W2l, b2, W2r, nullptr,
                                                          W4l, W4r, zbuf, rbuf);
    // layer 3b: out = mean(z) + r + b4
    k_final<<<(NN + 255) / 256, 256, 0, stream>>>(zbuf, rbuf, b4, row_start, csr_src, deg_inv, out);
}

// Round 4
// 208.947 us; speedup vs baseline: 1.2956x; 1.0843x over previous
//
#include <hip/hip_runtime.h>
#include <hip/hip_bf16.h>

// GraphSAGE 3-layer: 40 -> 64 -> 128 -> 3, mean aggregation over fixed edges.
// R17 (on R16): occupancy fix for the fused layers (they were latency-bound:
// MfmaUtil 1.1%, VALUBusy 20%, Occupancy 28% @ grid 782 = 3 blocks/CU).
//  - Weight fragments pre-packed into global scratch (wpack) by 13 extra
//    blocks on the k_bucket_cvt dispatch. k_fused reads B-frags as coalesced
//    short8 loads; the 16-37KB LDS weight-fill region is GONE.
//  - k_fused LDS = steady tiles only (9.2KB L1 / 17.9KB L2) -> 8 blocks/CU.
//  - Grid 782 -> 3125 (one 32-node chunk per block).
//  - A-frags loaded per-ks inside the MFMA loop (lower VGPR peak).

static constexpr int NN = 100000;
static constexpr int EE = 1600000;
static constexpr int NRANGE = 256;
static constexpr int RSIZE = (NN + NRANGE - 1) / NRANGE;   // 391
static constexpr int RPAD = 512;                           // pow2 >= RSIZE
static constexpr int NBUCKET = 8 * NRANGE;                 // 2048
static constexpr int CAP = 1024;     // per-bucket capacity (mean ~781, +8.7 sigma)
static constexpr int BCHUNK = 2048;  // edges per block (8 per thread)
static constexpr int BUCKET_BLOCKS = (EE + BCHUNK - 1) / BCHUNK;  // 782
static constexpr int CVT_BLOCKS = (NN * 40 / 8 + 255) / 256;      // 1954
static constexpr int NCHUNK = NN / 32;                            // 3125 exact

// packed weight-frag layout (shorts): W1 frags | W2 frags | W4 frags
static constexpr int W1OFF = 0;                 // 4 tiles * 4 ks * 64 lanes * 8
static constexpr int W2OFF = 4 * 4 * 64 * 8;    // 8192
static constexpr int W4OFF = W2OFF + 8 * 4 * 64 * 8;  // 24576
static constexpr int WPACK_SHORTS = W4OFF + 4 * 64 * 8;  // 26624
static constexpr int PACK_ITEMS = 4 * 4 * 64 + 8 * 4 * 64 + 4 * 64;  // 3328
static constexpr int PACK_BLOCKS = (PACK_ITEMS + 255) / 256;         // 13

typedef __attribute__((ext_vector_type(8))) short short8;
typedef __attribute__((ext_vector_type(4))) float f32x4;

__device__ __forceinline__ float bf2f(unsigned short u) {
    union { unsigned int i; float f; } c; c.i = ((unsigned int)u) << 16; return c.f;
}
__device__ __forceinline__ unsigned short f2bf(float f) {
    union { float f; unsigned int i; } c; c.f = f;
    unsigned int x = c.i;
    return (unsigned short)((x + 0x7fffu + ((x >> 16) & 1u)) >> 16);   // RNE
}

// ---------------- phase 1 (fused): bucket edges + x->bf16 convert + weight pack ----------------
__global__ __launch_bounds__(256) void k_bucket_cvt(const int* __restrict__ src, const int* __restrict__ dst,
                                                    int* __restrict__ pcur, unsigned int* __restrict__ pairs,
                                                    const float* __restrict__ x, unsigned short* __restrict__ xb,
                                                    const float* __restrict__ W1l, const float* __restrict__ W1r,
                                                    const float* __restrict__ W2l, const float* __restrict__ W2r,
                                                    const float* __restrict__ W4l, const float* __restrict__ W4r,
                                                    unsigned short* __restrict__ wpack) {
    __shared__ int cnt[NRANGE];
    __shared__ int base[NRANGE];
    const int tid = threadIdx.x;
    if (blockIdx.x >= BUCKET_BLOCKS + CVT_BLOCKS) {
        // ---- weight-pack branch: frag layout (t*KS+ks)*64+lane -> short8 ----
        int idx = (blockIdx.x - BUCKET_BLOCKS - CVT_BLOCKS) * 256 + tid;
        if (idx < PACK_ITEMS) {
            short8 v;
            if (idx < 1024) {                       // W1: Fin=40, 4 tiles
                int l = idx & 63, ks = (idx >> 6) & 3, t = idx >> 8;
                int o = t * 16 + (l & 15);
                int kbase = ks * 32 + (l >> 4) * 8;
#pragma unroll
                for (int j = 0; j < 8; ++j) {
                    int k = kbase + j; float w;
                    if (k < 64) w = (k < 40) ? W1l[o * 40 + k] : 0.f;
                    else { int k2 = k - 64; w = (k2 < 40) ? W1r[o * 40 + k2] : 0.f; }
                    v[j] = (short)f2bf(w);
                }
                *(short8*)&wpack[W1OFF + idx * 8] = v;
            } else if (idx < 3072) {                // W2: Fin=64, 8 tiles
                int i2 = idx - 1024;
                int l = i2 & 63, ks = (i2 >> 6) & 3, t = i2 >> 8;
                int o = t * 16 + (l & 15);
                int kbase = ks * 32 + (l >> 4) * 8;
#pragma unroll
                for (int j = 0; j < 8; ++j) {
                    int k = kbase + j;
                    float w = (k < 64) ? W2l[o * 64 + k] : W2r[o * 64 + (k - 64)];
                    v[j] = (short)f2bf(w);
                }
                *(short8*)&wpack[W2OFF + i2 * 8] = v;
            } else {                                // W4: [z|r] narrow, K=128
                int i4 = idx - 3072;
                int l = i4 & 63, ks = i4 >> 6;
                int o = l & 15;
                int kbase = ks * 32 + (l >> 4) * 8;
#pragma unroll
                for (int j = 0; j < 8; ++j) {
                    int k = kbase + j;
                    float w = 0.f;
                    if (o < 3) w = W4l[o * 128 + k];
                    else if (o >= 4 && o < 7) w = W4r[(o - 4) * 128 + k];
                    v[j] = (short)f2bf(w);
                }
                *(short8*)&wpack[W4OFF + i4 * 8] = v;
            }
        }
        return;
    }
    if (blockIdx.x >= BUCKET_BLOCKS) {
        // ---- convert branch: fp32 -> bf16 rows of x ----
        int i = (blockIdx.x - BUCKET_BLOCKS) * 256 + tid;
        if (i < NN * 40 / 8) {
            const float4* p = (const float4*)(x + (size_t)i * 8);
            float4 a = p[0], b = p[1];
            short8 v;
            v[0] = (short)f2bf(a.x); v[1] = (short)f2bf(a.y); v[2] = (short)f2bf(a.z); v[3] = (short)f2bf(a.w);
            v[4] = (short)f2bf(b.x); v[5] = (short)f2bf(b.y); v[6] = (short)f2bf(b.z); v[7] = (short)f2bf(b.w);
            *(short8*)(xb + (size_t)i * 8) = v;
        }
        return;
    }
    // ---- bucket branch: block-local reservation, packed (s | dloc<<17) ----
    const int part = blockIdx.x & 7;            // this block's XCD tag (round-robin)
    const int e0 = blockIdx.x * BCHUNK;
    cnt[tid] = 0;                               // NRANGE == blockDim == 256
    __syncthreads();
    int r_[8], lp_[8];
    unsigned int p_[8];
#pragma unroll
    for (int j = 0; j < 8; ++j) {
        int e = e0 + j * 256 + tid;
        r_[j] = -1;
        if (e < EE) {
            int d = dst[e];
            int s = src[e];
            int r = d / RSIZE;                  // const-divide -> magic mul
            r_[j] = r;
            p_[j] = (unsigned int)s | ((unsigned int)(d - r * RSIZE) << 17);
            lp_[j] = atomicAdd(&cnt[r], 1);     // fast LDS atomic
        }
    }
    __syncthreads();
    {
        int c = cnt[tid];
        base[tid] = (c > 0) ? atomicAdd(&pcur[(part << 8) | tid], c) : 0;  // 1 global RMW / bucket / block
    }
    __syncthreads();
#pragma unroll
    for (int j = 0; j < 8; ++j) {
        if (r_[j] >= 0) {
            int pos = base[r_[j]] + lp_[j];
            if (pos < CAP) pairs[(size_t)((part << 8) | r_[j]) * CAP + pos] = p_[j];
        }
    }
}

// ---------------- fused CSR build: degree count + scan + row_start/deg_inv + scatter ----------------
__global__ __launch_bounds__(1024) void k_build(const unsigned int* __restrict__ pairs,
                                                const int* __restrict__ pcur,
                                                int* __restrict__ row_start, float* __restrict__ deg_inv,
                                                int* __restrict__ csr_src) {
    __shared__ int ldeg[RPAD];
    __shared__ int lrs[RPAD];
    __shared__ int rtot[NRANGE];
    const int tid = threadIdx.x;
    const int r = blockIdx.x;
    const int lo = r * RSIZE;
    const int nloc = (lo + RSIZE <= NN) ? RSIZE : (NN - lo);
    for (int t = tid; t < RPAD; t += 1024) ldeg[t] = 0;
    __syncthreads();
    // pass 1: degree histogram
    for (int p = 0; p < 8; ++p) {
        int b = (p << 8) | r;
        int len = pcur[b]; if (len > CAP) len = CAP;
        const unsigned int* bp = pairs + (size_t)b * CAP;
        for (int i = tid; i < len; i += 1024)
            atomicAdd(&ldeg[bp[i] >> 17], 1);
    }
    // per-range totals from pcur (independent of ldeg)
    if (tid < NRANGE) {
        int s = 0;
#pragma unroll
        for (int p = 0; p < 8; ++p) {
            int c = pcur[(p << 8) | tid];
            s += (c > CAP) ? CAP : c;
        }
        rtot[tid] = s;
    }
    __syncthreads();
    // inclusive scan of rtot (256 values)
    for (int d = 1; d < NRANGE; d <<= 1) {
        int t = (tid < NRANGE && tid >= d) ? rtot[tid - d] : 0;
        __syncthreads();
        if (tid < NRANGE) rtot[tid] += t;
        __syncthreads();
    }
    const int rbase = (r == 0) ? 0 : rtot[r - 1];
    // inclusive scan of ldeg -> lrs (512 values)
    if (tid < RPAD) lrs[tid] = ldeg[tid];
    __syncthreads();
    for (int d = 1; d < RPAD; d <<= 1) {
        int t = (tid < RPAD && tid >= d) ? lrs[tid - d] : 0;
        __syncthreads();
        if (tid < RPAD) lrs[tid] += t;
        __syncthreads();
    }
    // write row_start / deg_inv; convert lrs to exclusive, reset ldeg to cursors
    int excl = 0, dg = 0;
    if (tid < RPAD) { dg = ldeg[tid]; excl = lrs[tid] - dg; }
    if (tid < nloc) {
        row_start[lo + tid] = rbase + excl;
        deg_inv[lo + tid] = (dg > 0) ? 1.0f / (float)dg : 0.0f;
    }
    if (r == 0 && tid == 0) row_start[NN] = EE;
    __syncthreads();
    if (tid < RPAD) { lrs[tid] = excl; ldeg[tid] = 0; }
    __syncthreads();
    // pass 2: scatter
    for (int p = 0; p < 8; ++p) {
        int b = (p << 8) | r;
        int len = pcur[b]; if (len > CAP) len = CAP;
        const unsigned int* bp = pairs + (size_t)b * CAP;
        for (int i = tid; i < len; i += 1024) {
            unsigned int pk = bp[i];
            int dloc = pk >> 17;
            int lp = atomicAdd(&ldeg[dloc], 1);             // LDS cursor
            csr_src[rbase + lrs[dloc] + lp] = (int)(pk & 0x1FFFFu);
        }
    }
}

// ---------------- fused layer: gather-mean (LDS) + MFMA GEMM [+ zr epilogue] ----------------
// One 32-node chunk per block (grid = 3125). B-frags read coalesced from wpack.
template<int Fin, int Fout, bool RELU, bool ZR, int WOFF>
__global__ __launch_bounds__(256) void k_fused(const unsigned short* __restrict__ xin,
                                               const int* __restrict__ row_start,
                                               const int* __restrict__ csr_src,
                                               const float* __restrict__ deg_inv,
                                               const unsigned short* __restrict__ wpack,
                                               const float* __restrict__ bias,
                                               unsigned short* __restrict__ out,
                                               float* __restrict__ z,
                                               float* __restrict__ rr_) {
    constexpr int KS = 4;
    constexpr int TILES = Fout / 16;
    constexpr int TPW = TILES / 4;              // tiles per wave
    constexpr int SMEAN = 0;                    // [32][72]
    constexpr int SROOT = 32 * 72;              // [32][72]
    constexpr int SH2 = 2 * 32 * 72;            // [32][136] (ZR only)
    constexpr int SHM = 2 * 32 * 72 + (ZR ? 32 * 136 : 0);
    __shared__ short shm[SHM];
    const int tid = threadIdx.x;
    const int lane = tid & 63;
    const int wv = tid >> 6;

    // ---- B-frags: coalesced short8 loads from packed weights ----
    short8 bfr[TPW][KS];
#pragma unroll
    for (int tt = 0; tt < TPW; ++tt)
#pragma unroll
        for (int ks = 0; ks < KS; ++ks)
            bfr[tt][ks] = *(const short8*)&wpack[WOFF + (((wv * TPW + tt) * KS + ks) * 64 + lane) * 8];
    short8 b4r[4];
    if constexpr (ZR) {
        if (wv < 2) {
#pragma unroll
            for (int ks = 0; ks < 4; ++ks)
                b4r[ks] = *(const short8*)&wpack[W4OFF + (ks * 64 + lane) * 8];
        }
    }
    float bias_t[TPW];
#pragma unroll
    for (int tt = 0; tt < TPW; ++tt) bias_t[tt] = bias[(wv * TPW + tt) * 16 + (lane & 15)];

    const int node8 = tid >> 3;                 // 0..31
    const int c = tid & 7;

    for (int ci = blockIdx.x; ci < NCHUNK; ci += gridDim.x) {
        const int nbase = ci * 32;
        // ---- phase A: gather-mean + root staging ----
        {
            const int node = nbase + node8;
            float acc[8] = {0, 0, 0, 0, 0, 0, 0, 0};
            short8 rv = {0, 0, 0, 0, 0, 0, 0, 0};
            if (c * 8 < Fin) {
                const unsigned short* xq = xin + c * 8;
                int rs = row_start[node], re = row_start[node + 1];
                int k = rs;
                for (; k + 4 <= re; k += 4) {
                    int s0 = csr_src[k], s1 = csr_src[k + 1], s2 = csr_src[k + 2], s3 = csr_src[k + 3];
                    short8 v0 = *(const short8*)(xq + (size_t)s0 * Fin);
                    short8 v1 = *(const short8*)(xq + (size_t)s1 * Fin);
                    short8 v2 = *(const short8*)(xq + (size_t)s2 * Fin);
                    short8 v3 = *(const short8*)(xq + (size_t)s3 * Fin);
#pragma unroll
                    for (int j = 0; j < 8; ++j)
                        acc[j] += (bf2f((unsigned short)v0[j]) + bf2f((unsigned short)v1[j]))
                                + (bf2f((unsigned short)v2[j]) + bf2f((unsigned short)v3[j]));
                }
                for (; k < re; ++k) {
                    short8 v0 = *(const short8*)(xq + (size_t)csr_src[k] * Fin);
#pragma unroll
                    for (int j = 0; j < 8; ++j) acc[j] += bf2f((unsigned short)v0[j]);
                }
                float di = deg_inv[node];
#pragma unroll
                for (int j = 0; j < 8; ++j) acc[j] *= di;
                rv = *(const short8*)(xin + (size_t)node * Fin + c * 8);
            }
            short8 mv;
#pragma unroll
            for (int j = 0; j < 8; ++j) mv[j] = (c * 8 < Fin) ? (short)f2bf(acc[j]) : (short)0;
            *(short8*)&shm[SMEAN + node8 * 72 + c * 8] = mv;
            *(short8*)&shm[SROOT + node8 * 72 + c * 8] = rv;
        }
        __syncthreads();
        // ---- phase B: MFMA (A-frags per-ks to keep VGPR low) ----
        f32x4 acc2[2][TPW];
#pragma unroll
        for (int m = 0; m < 2; ++m)
#pragma unroll
            for (int tt = 0; tt < TPW; ++tt) acc2[m][tt] = (f32x4){0.f, 0.f, 0.f, 0.f};
#pragma unroll
        for (int ks = 0; ks < KS; ++ks) {
            const int base = (ks < 2) ? SMEAN : SROOT;
            const int g = (ks & 1) * 4 + (lane >> 4);
            short8 a0 = *(const short8*)&shm[base + (lane & 15) * 72 + g * 8];
            short8 a1 = *(const short8*)&shm[base + (16 + (lane & 15)) * 72 + g * 8];
#pragma unroll
            for (int tt = 0; tt < TPW; ++tt) {
                acc2[0][tt] = __builtin_amdgcn_mfma_f32_16x16x32_bf16(a0, bfr[tt][ks], acc2[0][tt], 0, 0, 0);
                acc2[1][tt] = __builtin_amdgcn_mfma_f32_16x16x32_bf16(a1, bfr[tt][ks], acc2[1][tt], 0, 0, 0);
            }
        }
        if constexpr (!ZR) {
#pragma unroll
            for (int m = 0; m < 2; ++m) {
                int nrow = nbase + m * 16 + (lane >> 4) * 4;
#pragma unroll
                for (int tt = 0; tt < TPW; ++tt) {
                    int col = (wv * TPW + tt) * 16 + (lane & 15);
#pragma unroll
                    for (int q = 0; q < 4; ++q) {
                        float v = acc2[m][tt][q] + bias_t[tt];
                        if (RELU) v = fmaxf(v, 0.f);
                        out[(size_t)(nrow + q) * Fout + col] = f2bf(v);
                    }
                }
            }
        } else {
            // relu'd h2 tile -> LDS
#pragma unroll
            for (int m = 0; m < 2; ++m) {
                int row0 = m * 16 + (lane >> 4) * 4;
#pragma unroll
                for (int tt = 0; tt < TPW; ++tt) {
                    int col = (wv * TPW + tt) * 16 + (lane & 15);
#pragma unroll
                    for (int q = 0; q < 4; ++q) {
                        float v = acc2[m][tt][q] + bias_t[tt];
                        if (RELU) v = fmaxf(v, 0.f);
                        shm[SH2 + (row0 + q) * 136 + col] = (short)f2bf(v);
                    }
                }
            }
            __syncthreads();
            if (wv < 2) {
                const int row = wv * 16 + (lane & 15);
                f32x4 az = (f32x4){0.f, 0.f, 0.f, 0.f};
#pragma unroll
                for (int ks = 0; ks < 4; ++ks) {
                    short8 a4 = *(const short8*)&shm[SH2 + row * 136 + (ks * 4 + (lane >> 4)) * 8];
                    az = __builtin_amdgcn_mfma_f32_16x16x32_bf16(a4, b4r[ks], az, 0, 0, 0);
                }
                const int col = lane & 15;
                const int nr = nbase + wv * 16 + (lane >> 4) * 4;
                if (col < 3) {
#pragma unroll
                    for (int q = 0; q < 4; ++q) z[(size_t)(nr + q) * 4 + col] = az[q];
                } else if (col >= 4 && col < 7) {
#pragma unroll
                    for (int q = 0; q < 4; ++q) rr_[(size_t)(nr + q) * 4 + col - 4] = az[q];
                }
            }
        }
        __syncthreads();                        // protect shm reuse next chunk
    }
}

// ---------------- final: out = mean(z)[n] + r[n] + b4 ----------------
__global__ __launch_bounds__(256) void k_final(const float* __restrict__ z, const float* __restrict__ r,
                                               const float* __restrict__ b4,
                                               const int* __restrict__ row_start, const int* __restrict__ csr_src,
                                               const float* __restrict__ deg_inv, float* __restrict__ out) {
    int n = blockIdx.x * 256 + threadIdx.x;
    if (n >= NN) return;
    int rs = row_start[n], re = row_start[n + 1];
    float a0 = 0, a1 = 0, a2 = 0, b0 = 0, b1 = 0, b2 = 0;
    int k = rs;
    for (; k + 4 <= re; k += 4) {
        int s0 = csr_src[k], s1 = csr_src[k + 1], s2 = csr_src[k + 2], s3 = csr_src[k + 3];
        float4 z0 = *(const float4*)&z[4 * (size_t)s0];
        float4 z1 = *(const float4*)&z[4 * (size_t)s1];
        float4 z2 = *(const float4*)&z[4 * (size_t)s2];
        float4 z3 = *(const float4*)&z[4 * (size_t)s3];
        a0 += z0.x; a1 += z0.y; a2 += z0.z;
        b0 += z1.x; b1 += z1.y; b2 += z1.z;
        a0 += z2.x; a1 += z2.y; a2 += z2.z;
        b0 += z3.x; b1 += z3.y; b2 += z3.z;
    }
    for (; k < re; ++k) {
        float4 z0 = *(const float4*)&z[4 * (size_t)csr_src[k]];
        a0 += z0.x; a1 += z0.y; a2 += z0.z;
    }
    float di = deg_inv[n];
    float4 rn = *(const float4*)&r[4 * (size_t)n];
    out[(size_t)n * 3 + 0] = (a0 + b0) * di + rn.x + b4[0];
    out[(size_t)n * 3 + 1] = (a1 + b1) * di + rn.y + b4[1];
    out[(size_t)n * 3 + 2] = (a2 + b2) * di + rn.z + b4[2];
}

extern "C" void kernel_launch(void* const* d_in, const int* in_sizes, int n_in,
                              void* d_out, int out_size, void* d_ws, size_t ws_size,
                              hipStream_t stream) {
    const float* x   = (const float*)d_in[0];
    const int*   ei  = (const int*)d_in[1];
    const float* W1l = (const float*)d_in[2];
    const float* b1  = (const float*)d_in[3];
    const float* W1r = (const float*)d_in[4];
    const float* W2l = (const float*)d_in[5];
    const float* b2  = (const float*)d_in[6];
    const float* W2r = (const float*)d_in[7];
    const float* W4l = (const float*)d_in[8];
    const float* b4  = (const float*)d_in[9];
    const float* W4r = (const float*)d_in[10];
    float* out = (float*)d_out;

    char* ws = (char*)d_ws;
    size_t off = 0;
    auto alloc = [&](size_t bytes) -> void* {
        void* p = ws + off;
        off = (off + bytes + 255) & ~(size_t)255;
        return p;
    };
    int*   row_start = (int*)alloc(((size_t)NN + 1) * 4);
    int*   csr_src   = (int*)alloc((size_t)EE * 4);
    float* deg_inv   = (float*)alloc((size_t)NN * 4);
    int*   pcur      = (int*)alloc((size_t)NBUCKET * 4);
    unsigned short* xb    = (unsigned short*)alloc((size_t)NN * 40 * 2);
    unsigned short* h1    = (unsigned short*)alloc((size_t)NN * 64 * 2);
    unsigned short* wpack = (unsigned short*)alloc((size_t)WPACK_SHORTS * 2);
    float* zbuf = (float*)alloc((size_t)NN * 4 * 4);
    float* rbuf = (float*)alloc((size_t)NN * 4 * 4);
    unsigned int* pairs = (unsigned int*)alloc((size_t)NBUCKET * CAP * 4);   // 8.4 MB

    const int* e_src = ei;
    const int* e_dst = ei + EE;

    hipMemsetAsync(pcur, 0, (size_t)NBUCKET * 4, stream);

    // phase 1: bucket + x->bf16 + weight pack, one dispatch
    k_bucket_cvt<<<BUCKET_BLOCKS + CVT_BLOCKS + PACK_BLOCKS, 256, 0, stream>>>(
        e_src, e_dst, pcur, pairs, x, xb, W1l, W1r, W2l, W2r, W4l, W4r, wpack);
    // phase 2: fused degree + scan + row_start/deg_inv + scatter
    k_build<<<NRANGE, 1024, 0, stream>>>(pairs, pcur, row_start, deg_inv, csr_src);

    // layer 1: 40 -> 64 (fused gather + gemm)
    k_fused<40, 64, true, false, W1OFF><<<NCHUNK, 256, 0, stream>>>(
        xb, row_start, csr_src, deg_inv, wpack, b1, h1, nullptr, nullptr);
    // layer 2+3a: 64 -> 128 (fused gather + gemm + zr transform)
    k_fused<64, 128, true, true, W2OFF><<<NCHUNK, 256, 0, stream>>>(
        h1, row_start, csr_src, deg_inv, wpack, b2, nullptr, zbuf, rbuf);
    // layer 3b: out = mean(z) + r + b4
    k_final<<<(NN + 255) / 256, 256, 0, stream>>>(zbuf, rbuf, b4, row_start, csr_src, deg_inv, out);
}

// Round 5
// 196.101 us; speedup vs baseline: 1.3805x; 1.0655x over previous
//
#include <hip/hip_runtime.h>
#include <hip/hip_bf16.h>

// GraphSAGE 3-layer: 40 -> 64 -> 128 -> 3, mean aggregation over fixed edges.
// R18 (on R17): gather MLP fix. Fused layers were latency-bound (MfmaUtil 3%,
// VALUBusy 27%, HBM 25%): idx->row dependent chain only 4 deep.
//  - Chunk edge indices staged coalesced into LDS (lidx[1024], global
//    fallback) -> index level removed from the latency chain.
//  - Row loads 8-deep (full batches + masked clamped tail batch).
//  - k_final gather same treatment (8-deep, idx batch ahead of row batch).
//  - b4r frags loaded in epilogue only; single chunk per block (no loop).

static constexpr int NN = 100000;
static constexpr int EE = 1600000;
static constexpr int NRANGE = 256;
static constexpr int RSIZE = (NN + NRANGE - 1) / NRANGE;   // 391
static constexpr int RPAD = 512;                           // pow2 >= RSIZE
static constexpr int NBUCKET = 8 * NRANGE;                 // 2048
static constexpr int CAP = 1024;     // per-bucket capacity (mean ~781, +8.7 sigma)
static constexpr int BCHUNK = 2048;  // edges per block (8 per thread)
static constexpr int BUCKET_BLOCKS = (EE + BCHUNK - 1) / BCHUNK;  // 782
static constexpr int CVT_BLOCKS = (NN * 40 / 8 + 255) / 256;      // 1954
static constexpr int NCHUNK = NN / 32;                            // 3125 exact
static constexpr int EIDX = 1024;    // staged indices per chunk (mean 512, +22 sigma)

// packed weight-frag layout (shorts): W1 frags | W2 frags | W4 frags
static constexpr int W1OFF = 0;                 // 4 tiles * 4 ks * 64 lanes * 8
static constexpr int W2OFF = 4 * 4 * 64 * 8;    // 8192
static constexpr int W4OFF = W2OFF + 8 * 4 * 64 * 8;  // 24576
static constexpr int WPACK_SHORTS = W4OFF + 4 * 64 * 8;  // 26624
static constexpr int PACK_ITEMS = 4 * 4 * 64 + 8 * 4 * 64 + 4 * 64;  // 3328
static constexpr int PACK_BLOCKS = (PACK_ITEMS + 255) / 256;         // 13

typedef __attribute__((ext_vector_type(8))) short short8;
typedef __attribute__((ext_vector_type(4))) float f32x4;

__device__ __forceinline__ float bf2f(unsigned short u) {
    union { unsigned int i; float f; } c; c.i = ((unsigned int)u) << 16; return c.f;
}
__device__ __forceinline__ unsigned short f2bf(float f) {
    union { float f; unsigned int i; } c; c.f = f;
    unsigned int x = c.i;
    return (unsigned short)((x + 0x7fffu + ((x >> 16) & 1u)) >> 16);   // RNE
}

// ---------------- phase 1 (fused): bucket edges + x->bf16 convert + weight pack ----------------
__global__ __launch_bounds__(256) void k_bucket_cvt(const int* __restrict__ src, const int* __restrict__ dst,
                                                    int* __restrict__ pcur, unsigned int* __restrict__ pairs,
                                                    const float* __restrict__ x, unsigned short* __restrict__ xb,
                                                    const float* __restrict__ W1l, const float* __restrict__ W1r,
                                                    const float* __restrict__ W2l, const float* __restrict__ W2r,
                                                    const float* __restrict__ W4l, const float* __restrict__ W4r,
                                                    unsigned short* __restrict__ wpack) {
    __shared__ int cnt[NRANGE];
    __shared__ int base[NRANGE];
    const int tid = threadIdx.x;
    if (blockIdx.x >= BUCKET_BLOCKS + CVT_BLOCKS) {
        // ---- weight-pack branch: frag layout (t*KS+ks)*64+lane -> short8 ----
        int idx = (blockIdx.x - BUCKET_BLOCKS - CVT_BLOCKS) * 256 + tid;
        if (idx < PACK_ITEMS) {
            short8 v;
            if (idx < 1024) {                       // W1: Fin=40, 4 tiles
                int l = idx & 63, ks = (idx >> 6) & 3, t = idx >> 8;
                int o = t * 16 + (l & 15);
                int kbase = ks * 32 + (l >> 4) * 8;
#pragma unroll
                for (int j = 0; j < 8; ++j) {
                    int k = kbase + j; float w;
                    if (k < 64) w = (k < 40) ? W1l[o * 40 + k] : 0.f;
                    else { int k2 = k - 64; w = (k2 < 40) ? W1r[o * 40 + k2] : 0.f; }
                    v[j] = (short)f2bf(w);
                }
                *(short8*)&wpack[W1OFF + idx * 8] = v;
            } else if (idx < 3072) {                // W2: Fin=64, 8 tiles
                int i2 = idx - 1024;
                int l = i2 & 63, ks = (i2 >> 6) & 3, t = i2 >> 8;
                int o = t * 16 + (l & 15);
                int kbase = ks * 32 + (l >> 4) * 8;
#pragma unroll
                for (int j = 0; j < 8; ++j) {
                    int k = kbase + j;
                    float w = (k < 64) ? W2l[o * 64 + k] : W2r[o * 64 + (k - 64)];
                    v[j] = (short)f2bf(w);
                }
                *(short8*)&wpack[W2OFF + i2 * 8] = v;
            } else {                                // W4: [z|r] narrow, K=128
                int i4 = idx - 3072;
                int l = i4 & 63, ks = i4 >> 6;
                int o = l & 15;
                int kbase = ks * 32 + (l >> 4) * 8;
#pragma unroll
                for (int j = 0; j < 8; ++j) {
                    int k = kbase + j;
                    float w = 0.f;
                    if (o < 3) w = W4l[o * 128 + k];
                    else if (o >= 4 && o < 7) w = W4r[(o - 4) * 128 + k];
                    v[j] = (short)f2bf(w);
                }
                *(short8*)&wpack[W4OFF + i4 * 8] = v;
            }
        }
        return;
    }
    if (blockIdx.x >= BUCKET_BLOCKS) {
        // ---- convert branch: fp32 -> bf16 rows of x ----
        int i = (blockIdx.x - BUCKET_BLOCKS) * 256 + tid;
        if (i < NN * 40 / 8) {
            const float4* p = (const float4*)(x + (size_t)i * 8);
            float4 a = p[0], b = p[1];
            short8 v;
            v[0] = (short)f2bf(a.x); v[1] = (short)f2bf(a.y); v[2] = (short)f2bf(a.z); v[3] = (short)f2bf(a.w);
            v[4] = (short)f2bf(b.x); v[5] = (short)f2bf(b.y); v[6] = (short)f2bf(b.z); v[7] = (short)f2bf(b.w);
            *(short8*)(xb + (size_t)i * 8) = v;
        }
        return;
    }
    // ---- bucket branch: block-local reservation, packed (s | dloc<<17) ----
    const int part = blockIdx.x & 7;            // this block's XCD tag (round-robin)
    const int e0 = blockIdx.x * BCHUNK;
    cnt[tid] = 0;                               // NRANGE == blockDim == 256
    __syncthreads();
    int r_[8], lp_[8];
    unsigned int p_[8];
#pragma unroll
    for (int j = 0; j < 8; ++j) {
        int e = e0 + j * 256 + tid;
        r_[j] = -1;
        if (e < EE) {
            int d = dst[e];
            int s = src[e];
            int r = d / RSIZE;                  // const-divide -> magic mul
            r_[j] = r;
            p_[j] = (unsigned int)s | ((unsigned int)(d - r * RSIZE) << 17);
            lp_[j] = atomicAdd(&cnt[r], 1);     // fast LDS atomic
        }
    }
    __syncthreads();
    {
        int c = cnt[tid];
        base[tid] = (c > 0) ? atomicAdd(&pcur[(part << 8) | tid], c) : 0;  // 1 global RMW / bucket / block
    }
    __syncthreads();
#pragma unroll
    for (int j = 0; j < 8; ++j) {
        if (r_[j] >= 0) {
            int pos = base[r_[j]] + lp_[j];
            if (pos < CAP) pairs[(size_t)((part << 8) | r_[j]) * CAP + pos] = p_[j];
        }
    }
}

// ---------------- fused CSR build: degree count + scan + row_start/deg_inv + scatter ----------------
__global__ __launch_bounds__(1024) void k_build(const unsigned int* __restrict__ pairs,
                                                const int* __restrict__ pcur,
                                                int* __restrict__ row_start, float* __restrict__ deg_inv,
                                                int* __restrict__ csr_src) {
    __shared__ int ldeg[RPAD];
    __shared__ int lrs[RPAD];
    __shared__ int rtot[NRANGE];
    const int tid = threadIdx.x;
    const int r = blockIdx.x;
    const int lo = r * RSIZE;
    const int nloc = (lo + RSIZE <= NN) ? RSIZE : (NN - lo);
    for (int t = tid; t < RPAD; t += 1024) ldeg[t] = 0;
    __syncthreads();
    // pass 1: degree histogram
    for (int p = 0; p < 8; ++p) {
        int b = (p << 8) | r;
        int len = pcur[b]; if (len > CAP) len = CAP;
        const unsigned int* bp = pairs + (size_t)b * CAP;
        for (int i = tid; i < len; i += 1024)
            atomicAdd(&ldeg[bp[i] >> 17], 1);
    }
    // per-range totals from pcur (independent of ldeg)
    if (tid < NRANGE) {
        int s = 0;
#pragma unroll
        for (int p = 0; p < 8; ++p) {
            int c = pcur[(p << 8) | tid];
            s += (c > CAP) ? CAP : c;
        }
        rtot[tid] = s;
    }
    __syncthreads();
    // inclusive scan of rtot (256 values)
    for (int d = 1; d < NRANGE; d <<= 1) {
        int t = (tid < NRANGE && tid >= d) ? rtot[tid - d] : 0;
        __syncthreads();
        if (tid < NRANGE) rtot[tid] += t;
        __syncthreads();
    }
    const int rbase = (r == 0) ? 0 : rtot[r - 1];
    // inclusive scan of ldeg -> lrs (512 values)
    if (tid < RPAD) lrs[tid] = ldeg[tid];
    __syncthreads();
    for (int d = 1; d < RPAD; d <<= 1) {
        int t = (tid < RPAD && tid >= d) ? lrs[tid - d] : 0;
        __syncthreads();
        if (tid < RPAD) lrs[tid] += t;
        __syncthreads();
    }
    // write row_start / deg_inv; convert lrs to exclusive, reset ldeg to cursors
    int excl = 0, dg = 0;
    if (tid < RPAD) { dg = ldeg[tid]; excl = lrs[tid] - dg; }
    if (tid < nloc) {
        row_start[lo + tid] = rbase + excl;
        deg_inv[lo + tid] = (dg > 0) ? 1.0f / (float)dg : 0.0f;
    }
    if (r == 0 && tid == 0) row_start[NN] = EE;
    __syncthreads();
    if (tid < RPAD) { lrs[tid] = excl; ldeg[tid] = 0; }
    __syncthreads();
    // pass 2: scatter
    for (int p = 0; p < 8; ++p) {
        int b = (p << 8) | r;
        int len = pcur[b]; if (len > CAP) len = CAP;
        const unsigned int* bp = pairs + (size_t)b * CAP;
        for (int i = tid; i < len; i += 1024) {
            unsigned int pk = bp[i];
            int dloc = pk >> 17;
            int lp = atomicAdd(&ldeg[dloc], 1);             // LDS cursor
            csr_src[rbase + lrs[dloc] + lp] = (int)(pk & 0x1FFFFu);
        }
    }
}

// ---------------- fused layer: gather-mean (LDS) + MFMA GEMM [+ zr epilogue] ----------------
// One 32-node chunk per block (grid = 3125). Edge indices staged in LDS; row
// loads 8-deep. B-frags read coalesced from wpack.
template<int Fin, int Fout, bool RELU, bool ZR, int WOFF>
__global__ __launch_bounds__(256) void k_fused(const unsigned short* __restrict__ xin,
                                               const int* __restrict__ row_start,
                                               const int* __restrict__ csr_src,
                                               const float* __restrict__ deg_inv,
                                               const unsigned short* __restrict__ wpack,
                                               const float* __restrict__ bias,
                                               unsigned short* __restrict__ out,
                                               float* __restrict__ z,
                                               float* __restrict__ rr_) {
    constexpr int KS = 4;
    constexpr int TILES = Fout / 16;
    constexpr int TPW = TILES / 4;              // tiles per wave
    constexpr int SMEAN = 0;                    // [32][72]
    constexpr int SROOT = 32 * 72;              // [32][72]
    constexpr int SH2 = 2 * 32 * 72;            // [32][136] (ZR only)
    constexpr int SHM = 2 * 32 * 72 + (ZR ? 32 * 136 : 0);
    __shared__ short shm[SHM];
    __shared__ int lidx[EIDX];
    const int tid = threadIdx.x;
    const int lane = tid & 63;
    const int wv = tid >> 6;
    const int nbase = blockIdx.x * 32;

    // ---- B-frags: coalesced short8 loads from packed weights ----
    short8 bfr[TPW][KS];
#pragma unroll
    for (int tt = 0; tt < TPW; ++tt)
#pragma unroll
        for (int ks = 0; ks < KS; ++ks)
            bfr[tt][ks] = *(const short8*)&wpack[WOFF + (((wv * TPW + tt) * KS + ks) * 64 + lane) * 8];
    float bias_t[TPW];
#pragma unroll
    for (int tt = 0; tt < TPW; ++tt) bias_t[tt] = bias[(wv * TPW + tt) * 16 + (lane & 15)];

    // ---- phase A0: stage this chunk's edge indices into LDS (coalesced) ----
    const int rs_blk = row_start[nbase];
    const int re_blk = row_start[nbase + 32];
    const int nedge = re_blk - rs_blk;
    for (int i = tid; i < nedge && i < EIDX; i += 256) lidx[i] = csr_src[rs_blk + i];
    __syncthreads();

    const int node8 = tid >> 3;                 // 0..31
    const int c = tid & 7;

    // ---- phase A: gather-mean + root staging (rows 8-deep in flight) ----
    {
        const int node = nbase + node8;
        float acc[8] = {0, 0, 0, 0, 0, 0, 0, 0};
        short8 rv = {0, 0, 0, 0, 0, 0, 0, 0};
        if (c * 8 < Fin) {
            const unsigned short* xq = xin + c * 8;
            const int rs = row_start[node], re = row_start[node + 1];
            int k = rs;
            // full 8-batches
            for (; k + 8 <= re; k += 8) {
                short8 v[8];
#pragma unroll
                for (int j = 0; j < 8; ++j) {
                    int off = k + j - rs_blk;
                    int s = (off < EIDX) ? lidx[off] : csr_src[k + j];
                    v[j] = *(const short8*)(xq + (size_t)s * Fin);
                }
#pragma unroll
                for (int j = 0; j < 8; ++j)
#pragma unroll
                    for (int t = 0; t < 8; ++t) acc[t] += bf2f((unsigned short)v[j][t]);
            }
            // masked tail batch (loads clamped to re-1, contributions x0/x1)
            if (k < re) {
                short8 v[8];
#pragma unroll
                for (int j = 0; j < 8; ++j) {
                    int kk = (k + j < re) ? (k + j) : (re - 1);
                    int off = kk - rs_blk;
                    int s = (off < EIDX) ? lidx[off] : csr_src[kk];
                    v[j] = *(const short8*)(xq + (size_t)s * Fin);
                }
#pragma unroll
                for (int j = 0; j < 8; ++j) {
                    float m = (k + j < re) ? 1.f : 0.f;
#pragma unroll
                    for (int t = 0; t < 8; ++t) acc[t] += m * bf2f((unsigned short)v[j][t]);
                }
            }
            float di = deg_inv[node];
#pragma unroll
            for (int t = 0; t < 8; ++t) acc[t] *= di;
            rv = *(const short8*)(xin + (size_t)node * Fin + c * 8);
        }
        short8 mv;
#pragma unroll
        for (int t = 0; t < 8; ++t) mv[t] = (c * 8 < Fin) ? (short)f2bf(acc[t]) : (short)0;
        *(short8*)&shm[SMEAN + node8 * 72 + c * 8] = mv;
        *(short8*)&shm[SROOT + node8 * 72 + c * 8] = rv;
    }
    __syncthreads();
    // ---- phase B: MFMA (A-frags per-ks to keep VGPR low) ----
    f32x4 acc2[2][TPW];
#pragma unroll
    for (int m = 0; m < 2; ++m)
#pragma unroll
        for (int tt = 0; tt < TPW; ++tt) acc2[m][tt] = (f32x4){0.f, 0.f, 0.f, 0.f};
#pragma unroll
    for (int ks = 0; ks < KS; ++ks) {
        const int base = (ks < 2) ? SMEAN : SROOT;
        const int g = (ks & 1) * 4 + (lane >> 4);
        short8 a0 = *(const short8*)&shm[base + (lane & 15) * 72 + g * 8];
        short8 a1 = *(const short8*)&shm[base + (16 + (lane & 15)) * 72 + g * 8];
#pragma unroll
        for (int tt = 0; tt < TPW; ++tt) {
            acc2[0][tt] = __builtin_amdgcn_mfma_f32_16x16x32_bf16(a0, bfr[tt][ks], acc2[0][tt], 0, 0, 0);
            acc2[1][tt] = __builtin_amdgcn_mfma_f32_16x16x32_bf16(a1, bfr[tt][ks], acc2[1][tt], 0, 0, 0);
        }
    }
    if constexpr (!ZR) {
#pragma unroll
        for (int m = 0; m < 2; ++m) {
            int nrow = nbase + m * 16 + (lane >> 4) * 4;
#pragma unroll
            for (int tt = 0; tt < TPW; ++tt) {
                int col = (wv * TPW + tt) * 16 + (lane & 15);
#pragma unroll
                for (int q = 0; q < 4; ++q) {
                    float v = acc2[m][tt][q] + bias_t[tt];
                    if (RELU) v = fmaxf(v, 0.f);
                    out[(size_t)(nrow + q) * Fout + col] = f2bf(v);
                }
            }
        }
    } else {
        // relu'd h2 tile -> LDS
#pragma unroll
        for (int m = 0; m < 2; ++m) {
            int row0 = m * 16 + (lane >> 4) * 4;
#pragma unroll
            for (int tt = 0; tt < TPW; ++tt) {
                int col = (wv * TPW + tt) * 16 + (lane & 15);
#pragma unroll
                for (int q = 0; q < 4; ++q) {
                    float v = acc2[m][tt][q] + bias_t[tt];
                    if (RELU) v = fmaxf(v, 0.f);
                    shm[SH2 + (row0 + q) * 136 + col] = (short)f2bf(v);
                }
            }
        }
        __syncthreads();
        if (wv < 2) {
            short8 b4r[4];
#pragma unroll
            for (int ks = 0; ks < 4; ++ks)
                b4r[ks] = *(const short8*)&wpack[W4OFF + (ks * 64 + lane) * 8];
            const int row = wv * 16 + (lane & 15);
            f32x4 az = (f32x4){0.f, 0.f, 0.f, 0.f};
#pragma unroll
            for (int ks = 0; ks < 4; ++ks) {
                short8 a4 = *(const short8*)&shm[SH2 + row * 136 + (ks * 4 + (lane >> 4)) * 8];
                az = __builtin_amdgcn_mfma_f32_16x16x32_bf16(a4, b4r[ks], az, 0, 0, 0);
            }
            const int col = lane & 15;
            const int nr = nbase + wv * 16 + (lane >> 4) * 4;
            if (col < 3) {
#pragma unroll
                for (int q = 0; q < 4; ++q) z[(size_t)(nr + q) * 4 + col] = az[q];
            } else if (col >= 4 && col < 7) {
#pragma unroll
                for (int q = 0; q < 4; ++q) rr_[(size_t)(nr + q) * 4 + col - 4] = az[q];
            }
        }
    }
}

// ---------------- final: out = mean(z)[n] + r[n] + b4 (rows 8-deep) ----------------
__global__ __launch_bounds__(256) void k_final(const float* __restrict__ z, const float* __restrict__ r,
                                               const float* __restrict__ b4,
                                               const int* __restrict__ row_start, const int* __restrict__ csr_src,
                                               const float* __restrict__ deg_inv, float* __restrict__ out) {
    int n = blockIdx.x * 256 + threadIdx.x;
    if (n >= NN) return;
    const int rs = row_start[n], re = row_start[n + 1];
    float a0 = 0, a1 = 0, a2 = 0, b0 = 0, b1 = 0, b2 = 0;
    const float4* z4 = (const float4*)z;
    int k = rs;
    for (; k + 8 <= re; k += 8) {
        int e[8];
#pragma unroll
        for (int j = 0; j < 8; ++j) e[j] = csr_src[k + j];
        float4 v[8];
#pragma unroll
        for (int j = 0; j < 8; ++j) v[j] = z4[e[j]];
#pragma unroll
        for (int j = 0; j < 8; j += 2) {
            a0 += v[j].x; a1 += v[j].y; a2 += v[j].z;
            b0 += v[j + 1].x; b1 += v[j + 1].y; b2 += v[j + 1].z;
        }
    }
    if (k < re) {
        int e[8];
#pragma unroll
        for (int j = 0; j < 8; ++j) e[j] = csr_src[(k + j < re) ? (k + j) : (re - 1)];
        float4 v[8];
#pragma unroll
        for (int j = 0; j < 8; ++j) v[j] = z4[e[j]];
#pragma unroll
        for (int j = 0; j < 8; ++j) {
            float m = (k + j < re) ? 1.f : 0.f;
            a0 += m * v[j].x; a1 += m * v[j].y; a2 += m * v[j].z;
        }
    }
    float di = deg_inv[n];
    float4 rn = *(const float4*)&r[4 * (size_t)n];
    out[(size_t)n * 3 + 0] = (a0 + b0) * di + rn.x + b4[0];
    out[(size_t)n * 3 + 1] = (a1 + b1) * di + rn.y + b4[1];
    out[(size_t)n * 3 + 2] = (a2 + b2) * di + rn.z + b4[2];
}

extern "C" void kernel_launch(void* const* d_in, const int* in_sizes, int n_in,
                              void* d_out, int out_size, void* d_ws, size_t ws_size,
                              hipStream_t stream) {
    const float* x   = (const float*)d_in[0];
    const int*   ei  = (const int*)d_in[1];
    const float* W1l = (const float*)d_in[2];
    const float* b1  = (const float*)d_in[3];
    const float* W1r = (const float*)d_in[4];
    const float* W2l = (const float*)d_in[5];
    const float* b2  = (const float*)d_in[6];
    const float* W2r = (const float*)d_in[7];
    const float* W4l = (const float*)d_in[8];
    const float* b4  = (const float*)d_in[9];
    const float* W4r = (const float*)d_in[10];
    float* out = (float*)d_out;

    char* ws = (char*)d_ws;
    size_t off = 0;
    auto alloc = [&](size_t bytes) -> void* {
        void* p = ws + off;
        off = (off + bytes + 255) & ~(size_t)255;
        return p;
    };
    int*   row_start = (int*)alloc(((size_t)NN + 1) * 4);
    int*   csr_src   = (int*)alloc((size_t)EE * 4);
    float* deg_inv   = (float*)alloc((size_t)NN * 4);
    int*   pcur      = (int*)alloc((size_t)NBUCKET * 4);
    unsigned short* xb    = (unsigned short*)alloc((size_t)NN * 40 * 2);
    unsigned short* h1    = (unsigned short*)alloc((size_t)NN * 64 * 2);
    unsigned short* wpack = (unsigned short*)alloc((size_t)WPACK_SHORTS * 2);
    float* zbuf = (float*)alloc((size_t)NN * 4 * 4);
    float* rbuf = (float*)alloc((size_t)NN * 4 * 4);
    unsigned int* pairs = (unsigned int*)alloc((size_t)NBUCKET * CAP * 4);   // 8.4 MB

    const int* e_src = ei;
    const int* e_dst = ei + EE;

    hipMemsetAsync(pcur, 0, (size_t)NBUCKET * 4, stream);

    // phase 1: bucket + x->bf16 + weight pack, one dispatch
    k_bucket_cvt<<<BUCKET_BLOCKS + CVT_BLOCKS + PACK_BLOCKS, 256, 0, stream>>>(
        e_src, e_dst, pcur, pairs, x, xb, W1l, W1r, W2l, W2r, W4l, W4r, wpack);
    // phase 2: fused degree + scan + row_start/deg_inv + scatter
    k_build<<<NRANGE, 1024, 0, stream>>>(pairs, pcur, row_start, deg_inv, csr_src);

    // layer 1: 40 -> 64 (fused gather + gemm)
    k_fused<40, 64, true, false, W1OFF><<<NCHUNK, 256, 0, stream>>>(
        xb, row_start, csr_src, deg_inv, wpack, b1, h1, nullptr, nullptr);
    // layer 2+3a: 64 -> 128 (fused gather + gemm + zr transform)
    k_fused<64, 128, true, true, W2OFF><<<NCHUNK, 256, 0, stream>>>(
        h1, row_start, csr_src, deg_inv, wpack, b2, nullptr, zbuf, rbuf);
    // layer 3b: out = mean(z) + r + b4
    k_final<<<(NN + 255) / 256, 256, 0, stream>>>(zbuf, rbuf, b4, row_start, csr_src, deg_inv, out);
}